// Round 6
// baseline (231.682 us; speedup 1.0000x reference)
//
#include <hip/hip_runtime.h>
#include <hip/hip_bf16.h>

// Problem constants
#define B_   2
#define LQ_  2048
#define NH_  8
#define HB_  16      // NH_*B_
#define DM_  512
#define DK_  64

// temper = sqrt(d_model); scores computed in log2-space:
// SCALE_T = (1/sqrt(512)) * log2(e), folded into Q at projection time
#define SCALE_T (0.04419417382415922f * 1.4426950408889634f)

typedef short s16x8 __attribute__((ext_vector_type(8)));   // 8 bf16 (4 VGPRs)
typedef float f32x4 __attribute__((ext_vector_type(4)));   // MFMA 16x16 C/D

__device__ __forceinline__ float bf2f(unsigned short u){
  return __uint_as_float(((unsigned)u) << 16);
}
__device__ __forceinline__ ushort f2bfbits(float f){
  __hip_bfloat16 h = __float2bfloat16(f);
  union { __hip_bfloat16 h; ushort u; } cv; cv.h = h; return cv.u;
}

// ---------------------------------------------------------------------------
// P1: cast q,k,v (fp32 [4096][512]) -> bf16 (uint4 = 8 elts / thread)
// ---------------------------------------------------------------------------
__global__ __launch_bounds__(256) void cast_qkv(
    const float* __restrict__ q, const float* __restrict__ k, const float* __restrict__ v,
    ushort* __restrict__ qb, ushort* __restrict__ kb, ushort* __restrict__ vb){
  const float* src = (blockIdx.y == 0) ? q : (blockIdx.y == 1) ? k : v;
  ushort* dst      = (blockIdx.y == 0) ? qb : (blockIdx.y == 1) ? kb : vb;
  long i = (long)blockIdx.x * 256 + threadIdx.x;   // 262144 threads, 8 elts each
  float4 a = *(const float4*)(src + i * 8);
  float4 b = *(const float4*)(src + i * 8 + 4);
  uint4 p;
  p.x = (uint)f2bfbits(a.x) | ((uint)f2bfbits(a.y) << 16);
  p.y = (uint)f2bfbits(a.z) | ((uint)f2bfbits(a.w) << 16);
  p.z = (uint)f2bfbits(b.x) | ((uint)f2bfbits(b.y) << 16);
  p.w = (uint)f2bfbits(b.z) | ((uint)f2bfbits(b.w) << 16);
  *(uint4*)(dst + i * 8) = p;
}

// ---------------------------------------------------------------------------
// P2: repack per-head weights (h,d,ko) fp32 -> bf16 [n=h*64+ko][d]
// LDS 64x64 transpose tile: coalesced reads AND writes.
// grid (8 d-tiles, 8 h, 3 which)
// ---------------------------------------------------------------------------
__global__ __launch_bounds__(256) void repack_w(
    const float* __restrict__ wq, const float* __restrict__ wk, const float* __restrict__ wv,
    ushort* __restrict__ wqT, ushort* __restrict__ wkT, ushort* __restrict__ wvT){
  const int which = blockIdx.z;
  const float* src = (which == 0) ? wq : (which == 1) ? wk : wv;
  ushort* dst      = (which == 0) ? wqT : (which == 1) ? wkT : wvT;
  const int h  = blockIdx.y;
  const int d0 = blockIdx.x * 64;
  const int tid = threadIdx.x;
  __shared__ float t[64][65];

  for (int i = tid; i < 64 * 16; i += 256){
    int dd = i >> 4, c4 = (i & 15) * 4;
    float4 v = *(const float4*)(src + ((long)(h * DM_ + d0 + dd)) * DK_ + c4);
    t[dd][c4] = v.x; t[dd][c4+1] = v.y; t[dd][c4+2] = v.z; t[dd][c4+3] = v.w;
  }
  __syncthreads();
  for (int i = tid; i < 512; i += 256){
    int ko = i >> 3, g = (i & 7) * 8;
    uint4 p;
    p.x = (uint)f2bfbits(t[g+0][ko]) | ((uint)f2bfbits(t[g+1][ko]) << 16);
    p.y = (uint)f2bfbits(t[g+2][ko]) | ((uint)f2bfbits(t[g+3][ko]) << 16);
    p.z = (uint)f2bfbits(t[g+4][ko]) | ((uint)f2bfbits(t[g+5][ko]) << 16);
    p.w = (uint)f2bfbits(t[g+6][ko]) | ((uint)f2bfbits(t[g+7][ko]) << 16);
    *(uint4*)(dst + ((long)(h * DK_ + ko)) * DM_ + d0 + g) = p;
  }
}

// ---------------------------------------------------------------------------
// P3: extract lin_w[:, :512] -> bf16 [512][512]
// ---------------------------------------------------------------------------
__global__ __launch_bounds__(256) void extract_lw1(
    const float* __restrict__ lw, ushort* __restrict__ lwb1){
  int i = blockIdx.x * 256 + threadIdx.x;   // 32768 threads, 8 elts each
  int row = i >> 6, g = (i & 63) * 8;
  const float* s = lw + (long)row * 1024 + g;
  float4 a = *(const float4*)(s);
  float4 b = *(const float4*)(s + 4);
  uint4 p;
  p.x = (uint)f2bfbits(a.x) | ((uint)f2bfbits(a.y) << 16);
  p.y = (uint)f2bfbits(a.z) | ((uint)f2bfbits(a.w) << 16);
  p.z = (uint)f2bfbits(b.x) | ((uint)f2bfbits(b.y) << 16);
  p.w = (uint)f2bfbits(b.z) | ((uint)f2bfbits(b.w) << 16);
  *(uint4*)(lwb1 + (long)row * DM_ + g) = p;
}

// ---------------------------------------------------------------------------
// P4: W2 = lin_w[:,512:] @ pw  -> bf16 [512 i][512 k]   (fp32 VALU, small)
// 8 i-rows/block, 128 thr, thread owns 4 consecutive k.
// ---------------------------------------------------------------------------
__global__ __launch_bounds__(128) void w2_gemm(
    const float* __restrict__ lw, const float* __restrict__ pw,
    ushort* __restrict__ w2b){
  const int row0 = blockIdx.x * 8;
  const int tid  = threadIdx.x;
  __shared__ float xs[8][512];
  for (int i = tid; i < 8 * (DM_/4); i += 128){
    int r = i >> 7, c = (i & 127) * 4;
    float4 v = *(const float4*)(lw + (long)(row0 + r) * 1024 + 512 + c);
    xs[r][c] = v.x; xs[r][c+1] = v.y; xs[r][c+2] = v.z; xs[r][c+3] = v.w;
  }
  __syncthreads();

  const int o = tid * 4;
  float acc[8][4];
  #pragma unroll
  for (int r = 0; r < 8; ++r){ acc[r][0]=0.f; acc[r][1]=0.f; acc[r][2]=0.f; acc[r][3]=0.f; }

  for (int d = 0; d < DM_; ++d){
    float4 wv = *(const float4*)(pw + (long)d * DM_ + o);
    #pragma unroll
    for (int r = 0; r < 8; ++r){
      float xd = xs[r][d];
      acc[r][0] += xd * wv.x; acc[r][1] += xd * wv.y;
      acc[r][2] += xd * wv.z; acc[r][3] += xd * wv.w;
    }
  }
  #pragma unroll
  for (int r = 0; r < 8; ++r){
    ushort4 u;
    u.x = f2bfbits(acc[r][0]); u.y = f2bfbits(acc[r][1]);
    u.z = f2bfbits(acc[r][2]); u.w = f2bfbits(acc[r][3]);
    *(ushort4*)(w2b + (long)(row0 + r) * DM_ + o) = u;
  }
}

// ---------------------------------------------------------------------------
// P5: bias2[i] = lb[i] + sum_n lin_w[i][512+n] * pb[n]   (tiny)
// ---------------------------------------------------------------------------
__global__ __launch_bounds__(256) void bias2_k(
    const float* __restrict__ lw, const float* __restrict__ pb,
    const float* __restrict__ lb, float* __restrict__ bias2){
  int i = blockIdx.x * 256 + threadIdx.x;
  if (i >= DM_) return;
  float acc = 0.f;
  const float* row = lw + (long)i * 1024 + 512;
  for (int n = 0; n < DM_; ++n) acc += row[n] * pb[n];
  bias2[i] = lb[i] + acc;
}

// ---------------------------------------------------------------------------
// G1: head-projection GEMMs (z=0,1,2 -> q,k,v). A bf16 [4096][512],
// Bt bf16 [512][512] ([n][d]); C bf16 head-layout [(h*B+b)][l][64].
// z=0 pre-scaled by SCALE_T (log2-space scores).
// Block 256 thr = 4 waves, tile 64x64, K-step 64. LDS XOR-swizzled (r&7)<<4.
// ---------------------------------------------------------------------------
__global__ __launch_bounds__(256) void gemm_qkv(
    const ushort* __restrict__ qb, const ushort* __restrict__ kb, const ushort* __restrict__ vb,
    const ushort* __restrict__ wqT, const ushort* __restrict__ wkT, const ushort* __restrict__ wvT,
    ushort* __restrict__ qhb, ushort* __restrict__ khb, ushort* __restrict__ vhb){
  const int which = blockIdx.z;
  const ushort* A  = (which == 0) ? qb : (which == 1) ? kb : vb;
  const ushort* Bt = (which == 0) ? wqT : (which == 1) ? wkT : wvT;
  ushort* C        = (which == 0) ? qhb : (which == 1) ? khb : vhb;
  const float scale = (which == 0) ? SCALE_T : 1.0f;

  const int m0 = blockIdx.x * 64;
  const int n0 = blockIdx.y * 64;
  const int tid = threadIdx.x;
  const int wid = tid >> 6, lane = tid & 63;
  const int l15 = lane & 15, l4 = lane >> 4;

  __shared__ ushort as_[64 * 64];
  __shared__ ushort bs_[64 * 64];

  f32x4 acc[4];
  #pragma unroll
  for (int ct = 0; ct < 4; ++ct){ acc[ct][0]=0.f; acc[ct][1]=0.f; acc[ct][2]=0.f; acc[ct][3]=0.f; }

  for (int k0 = 0; k0 < DM_; k0 += 64){
    __syncthreads();
    for (int i = tid; i < 512; i += 256){
      int r = i >> 3, c = i & 7;
      uint4 av = *(const uint4*)(A + (long)(m0 + r) * DM_ + k0 + c * 8);
      *(uint4*)((char*)as_ + r * 128 + ((c * 16) ^ ((r & 7) << 4))) = av;
      uint4 bv = *(const uint4*)(Bt + (long)(n0 + r) * DM_ + k0 + c * 8);
      *(uint4*)((char*)bs_ + r * 128 + ((c * 16) ^ ((r & 7) << 4))) = bv;
    }
    __syncthreads();

    const char* arow = (const char*)as_ + (wid * 16 + l15) * 128;
    const int swz = (l15 & 7) << 4;
    s16x8 a0 = *(const s16x8*)(arow + ((l4 * 16) ^ swz));
    s16x8 a1 = *(const s16x8*)(arow + ((64 + l4 * 16) ^ swz));
    #pragma unroll
    for (int ct = 0; ct < 4; ++ct){
      const char* brow = (const char*)bs_ + (ct * 16 + l15) * 128;
      s16x8 b0 = *(const s16x8*)(brow + ((l4 * 16) ^ swz));
      s16x8 b1 = *(const s16x8*)(brow + ((64 + l4 * 16) ^ swz));
      acc[ct] = __builtin_amdgcn_mfma_f32_16x16x32_bf16(a0, b0, acc[ct], 0, 0, 0);
      acc[ct] = __builtin_amdgcn_mfma_f32_16x16x32_bf16(a1, b1, acc[ct], 0, 0, 0);
    }
  }

  #pragma unroll
  for (int ct = 0; ct < 4; ++ct){
    int col = n0 + ct * 16 + l15;
    int h = col >> 6, ko = col & 63;
    #pragma unroll
    for (int r = 0; r < 4; ++r){
      int m = m0 + wid * 16 + l4 * 4 + r;
      int b = m >> 11, l = m & 2047;
      C[(((long)h * B_ + b) * LQ_ + l) * DK_ + ko] = f2bfbits(acc[ct][r] * scale);
    }
  }
}

// ---------------------------------------------------------------------------
// G2: final fused GEMM  out0 = [q|oh] @ [lin_w1 | W2]^T + bias2.  K=1024.
// A1=qb, A2=ohb (both bf16 stride 512); Bt1=lwb1, Bt2=w2b.
// ---------------------------------------------------------------------------
__global__ __launch_bounds__(256) void gemm_final(
    const ushort* __restrict__ qb, const ushort* __restrict__ ohb,
    const ushort* __restrict__ lwb1, const ushort* __restrict__ w2b,
    const float* __restrict__ bias2, float* __restrict__ out0){
  const int m0 = blockIdx.x * 64;
  const int n0 = blockIdx.y * 64;
  const int tid = threadIdx.x;
  const int wid = tid >> 6, lane = tid & 63;
  const int l15 = lane & 15, l4 = lane >> 4;

  __shared__ ushort as_[64 * 64];
  __shared__ ushort bs_[64 * 64];

  f32x4 acc[4];
  #pragma unroll
  for (int ct = 0; ct < 4; ++ct){ acc[ct][0]=0.f; acc[ct][1]=0.f; acc[ct][2]=0.f; acc[ct][3]=0.f; }

  for (int k0 = 0; k0 < 2 * DM_; k0 += 64){
    const ushort* A  = (k0 < DM_) ? qb : ohb;
    const ushort* Bt = (k0 < DM_) ? lwb1 : w2b;
    const int kk = k0 & (DM_ - 1);
    __syncthreads();
    for (int i = tid; i < 512; i += 256){
      int r = i >> 3, c = i & 7;
      uint4 av = *(const uint4*)(A + (long)(m0 + r) * DM_ + kk + c * 8);
      *(uint4*)((char*)as_ + r * 128 + ((c * 16) ^ ((r & 7) << 4))) = av;
      uint4 bv = *(const uint4*)(Bt + (long)(n0 + r) * DM_ + kk + c * 8);
      *(uint4*)((char*)bs_ + r * 128 + ((c * 16) ^ ((r & 7) << 4))) = bv;
    }
    __syncthreads();

    const char* arow = (const char*)as_ + (wid * 16 + l15) * 128;
    const int swz = (l15 & 7) << 4;
    s16x8 a0 = *(const s16x8*)(arow + ((l4 * 16) ^ swz));
    s16x8 a1 = *(const s16x8*)(arow + ((64 + l4 * 16) ^ swz));
    #pragma unroll
    for (int ct = 0; ct < 4; ++ct){
      const char* brow = (const char*)bs_ + (ct * 16 + l15) * 128;
      s16x8 b0 = *(const s16x8*)(brow + ((l4 * 16) ^ swz));
      s16x8 b1 = *(const s16x8*)(brow + ((64 + l4 * 16) ^ swz));
      acc[ct] = __builtin_amdgcn_mfma_f32_16x16x32_bf16(a0, b0, acc[ct], 0, 0, 0);
      acc[ct] = __builtin_amdgcn_mfma_f32_16x16x32_bf16(a1, b1, acc[ct], 0, 0, 0);
    }
  }

  #pragma unroll
  for (int ct = 0; ct < 4; ++ct){
    int col = n0 + ct * 16 + l15;
    float bb = bias2[col];
    #pragma unroll
    for (int r = 0; r < 4; ++r){
      int m = m0 + wid * 16 + l4 * 4 + r;
      out0[(long)m * DM_ + col] = acc[ct][r] + bb;
    }
  }
}

// ---------------------------------------------------------------------------
// K2: MFMA scores + branch-free top-1 softmax (log2-space). NO LDS:
// per-head K (256 KB) is L2-resident; B-fragments loaded directly from global.
// ---------------------------------------------------------------------------
__global__ __launch_bounds__(256) void attn_top1_mfma(
    const ushort* __restrict__ qhb, const ushort* __restrict__ khb,
    float* __restrict__ pmax, int* __restrict__ amax){
  const int hb  = blockIdx.x;
  const int q0  = blockIdx.y * 64;
  const int tid = threadIdx.x;
  const int wid  = tid >> 6;
  const int lane = tid & 63;
  const int l15  = lane & 15;
  const int l4   = lane >> 4;

  const ushort* qrow = qhb + ((long)hb * LQ_ + q0 + wid * 16 + l15) * DK_;
  s16x8 aq0 = *(const s16x8*)(qrow +  0 + l4 * 8);
  s16x8 aq1 = *(const s16x8*)(qrow + 32 + l4 * 8);

  float m[4], sum[4]; int arg[4];
  #pragma unroll
  for (int r = 0; r < 4; ++r){ m[r] = -1e30f; sum[r] = 0.f; arg[r] = 0; }

  const ushort* kb0 = khb + (long)hb * LQ_ * DK_;
  for (int jt = 0; jt < LQ_ / 64; ++jt){
    f32x4 acc[4];
    #pragma unroll
    for (int ct = 0; ct < 4; ++ct){
      const ushort* krow = kb0 + (long)(jt * 64 + ct * 16 + l15) * DK_ + l4 * 8;
      s16x8 b0 = *(const s16x8*)(krow);
      s16x8 b1 = *(const s16x8*)(krow + 32);
      f32x4 c; c[0]=0.f; c[1]=0.f; c[2]=0.f; c[3]=0.f;
      c = __builtin_amdgcn_mfma_f32_16x16x32_bf16(aq0, b0, c, 0, 0, 0);
      c = __builtin_amdgcn_mfma_f32_16x16x32_bf16(aq1, b1, c, 0, 0, 0);
      acc[ct] = c;
    }

    #pragma unroll
    for (int ct = 0; ct < 4; ++ct){
      int col = jt * 64 + ct * 16 + l15;
      #pragma unroll
      for (int r = 0; r < 4; ++r){
        float t = acc[ct][r];
        sum[r] += exp2f(t);
        bool gt = t > m[r];
        arg[r] = gt ? col : arg[r];
        m[r]   = gt ? t : m[r];
      }
    }
  }

  #pragma unroll
  for (int off = 1; off < 16; off <<= 1){
    #pragma unroll
    for (int r = 0; r < 4; ++r){
      float m2 = __shfl_xor(m[r], off);
      float s2 = __shfl_xor(sum[r], off);
      int   a2 = __shfl_xor(arg[r], off);
      sum[r] += s2;
      bool take = (m2 > m[r]) || (m2 == m[r] && a2 < arg[r]);
      arg[r] = take ? a2 : arg[r];
      m[r]   = take ? m2 : m[r];
    }
  }

  if (l15 == 0){
    #pragma unroll
    for (int r = 0; r < 4; ++r){
      long row = (long)hb * LQ_ + q0 + wid * 16 + l4 * 4 + r;
      pmax[row] = exp2f(m[r]) / sum[r];
      amax[row] = arg[r];
    }
  }
}

// ---------------------------------------------------------------------------
// K3: gather oh rows = pmax * vhb[argmax]  (bf16 in, bf16 out)
// ---------------------------------------------------------------------------
__global__ __launch_bounds__(256) void gather_oh(
    const ushort* __restrict__ vhb, const float* __restrict__ pmax,
    const int* __restrict__ amax, ushort* __restrict__ ohb){
  int row  = blockIdx.x * 4 + (threadIdx.x >> 6);
  int lane = threadIdx.x & 63;
  int hb = row >> 11, q = row & 2047;
  int h = hb >> 1, b = hb & 1;
  float p = pmax[row];
  int a = amax[row];
  float val = bf2f(vhb[((long)hb * LQ_ + a) * DK_ + lane]);
  ohb[((long)(b * LQ_ + q)) * DM_ + h * DK_ + lane] = f2bfbits(p * val);
}

// ---------------------------------------------------------------------------
// K4: fused zero + scatter of the attn output region (runs LAST).
// ---------------------------------------------------------------------------
__global__ __launch_bounds__(256) void write_attn(
    const float* __restrict__ pmax, const int* __restrict__ amax,
    float* __restrict__ attn_out){
  int row  = blockIdx.x * 4 + (threadIdx.x >> 6);
  int lane = threadIdx.x & 63;
  float p = pmax[row];
  int a = amax[row];
  float4* rowp = (float4*)(attn_out + (long)row * LQ_);
  #pragma unroll
  for (int i = 0; i < 8; ++i){
    int f4idx = i * 64 + lane;        // 512 float4s per row
    int col0  = f4idx * 4;
    float4 z = make_float4(0.f, 0.f, 0.f, 0.f);
    if (a >= col0 && a < col0 + 4){
      int r = a - col0;
      if      (r == 0) z.x = p;
      else if (r == 1) z.y = p;
      else if (r == 2) z.z = p;
      else             z.w = p;
    }
    rowp[f4idx] = z;
  }
}

// ---------------------------------------------------------------------------
extern "C" void kernel_launch(void* const* d_in, const int* in_sizes, int n_in,
                              void* d_out, int out_size, void* d_ws, size_t ws_size,
                              hipStream_t stream){
  const float* q  = (const float*)d_in[0];
  const float* k  = (const float*)d_in[1];
  const float* v  = (const float*)d_in[2];
  const float* wq = (const float*)d_in[3];
  const float* wk = (const float*)d_in[4];
  const float* wv = (const float*)d_in[5];
  const float* pw = (const float*)d_in[6];
  const float* pb = (const float*)d_in[7];
  const float* lw = (const float*)d_in[8];
  const float* lb = (const float*)d_in[9];

  float* out0     = (float*)d_out;                    // (2,2048,512)
  float* attn_out = out0 + (long)B_ * LQ_ * DM_;      // (16,2048,2048) = 67.1M floats

  // Scratch lives INSIDE the attn output region; all dead before write_attn.
  ushort* qb   = (ushort*)attn_out;                   // [4096][512] bf16 (4 MB)
  ushort* kb   = qb  + (long)4096 * DM_;
  ushort* vb   = kb  + (long)4096 * DM_;
  ushort* wqT  = vb  + (long)4096 * DM_;              // [512][512] bf16 (512 KB)
  ushort* wkT  = wqT + (long)DM_ * DM_;
  ushort* wvT  = wkT + (long)DM_ * DM_;
  ushort* qhb  = wvT + (long)DM_ * DM_;               // head layout bf16 (4 MB)
  ushort* khb  = qhb + (long)HB_ * LQ_ * DK_;
  ushort* vhb  = khb + (long)HB_ * LQ_ * DK_;
  ushort* ohb  = vhb + (long)HB_ * LQ_ * DK_;         // [4096][512] bf16 (4 MB)
  ushort* lwb1 = ohb + (long)4096 * DM_;              // [512][512] bf16
  ushort* w2b  = lwb1 + (long)DM_ * DM_;              // [512][512] bf16
  float*  bias2 = (float*)(w2b + (long)DM_ * DM_);    // 512 fp32
  // total ~34 MB << 268 MB region

  // d_ws: per-row stats (256 KB) — must survive write_attn.
  float* pmax = (float*)d_ws;                          // 16*2048 floats
  int*   amax = (int*)(pmax + (long)HB_ * LQ_);        // 16*2048 ints

  // prep
  cast_qkv<<<dim3(1024, 3), 256, 0, stream>>>(q, k, v, qb, kb, vb);
  repack_w<<<dim3(8, 8, 3), 256, 0, stream>>>(wq, wk, wv, wqT, wkT, wvT);
  extract_lw1<<<128, 256, 0, stream>>>(lw, lwb1);
  w2_gemm<<<64, 128, 0, stream>>>(lw, pw, w2b);
  bias2_k<<<2, 256, 0, stream>>>(lw, pb, lb, bias2);

  // head projections (q,k,v) via one MFMA GEMM launch
  gemm_qkv<<<dim3(64, 8, 3), 256, 0, stream>>>(qb, kb, vb, wqT, wkT, wvT, qhb, khb, vhb);

  // MFMA scores + branch-free top-1 softmax (no LDS)
  attn_top1_mfma<<<dim3(HB_, LQ_/64), 256, 0, stream>>>(qhb, khb, pmax, amax);

  // gather PV rows -> ohb (bf16)
  gather_oh<<<HB_*LQ_/4, 256, 0, stream>>>(vhb, pmax, amax, ohb);

  // fused proj+lin: out0 = [q|oh] @ [lin_w1 | W2]^T + bias2
  gemm_final<<<dim3(64, 8), 256, 0, stream>>>(qb, ohb, lwb1, w2b, bias2, out0);

  // LAST: rewrite the whole attn region with zeros + scattered p values
  write_attn<<<HB_*LQ_/4, 256, 0, stream>>>(pmax, amax, attn_out);
}

// Round 7
// 179.796 us; speedup vs baseline: 1.2886x; 1.2886x over previous
//
#include <hip/hip_runtime.h>
#include <hip/hip_bf16.h>

// Problem constants
#define B_   2
#define LQ_  2048
#define NH_  8
#define HB_  16      // NH_*B_
#define DM_  512
#define DK_  64

// temper = sqrt(d_model); scores computed in log2-space:
// SCALE_T = (1/sqrt(512)) * log2(e), folded into Q at projection time
#define SCALE_T (0.04419417382415922f * 1.4426950408889634f)

typedef short s16x8 __attribute__((ext_vector_type(8)));   // 8 bf16 (4 VGPRs)
typedef float f32x4 __attribute__((ext_vector_type(4)));   // MFMA 16x16 C/D

__device__ __forceinline__ ushort f2bfbits(float f){
  __hip_bfloat16 h = __float2bfloat16(f);
  union { __hip_bfloat16 h; ushort u; } cv; cv.h = h; return cv.u;
}
__device__ __forceinline__ uint4 pack8(float4 v0, float4 v1){
  uint4 p;
  p.x = (uint)f2bfbits(v0.x) | ((uint)f2bfbits(v0.y) << 16);
  p.y = (uint)f2bfbits(v0.z) | ((uint)f2bfbits(v0.w) << 16);
  p.z = (uint)f2bfbits(v1.x) | ((uint)f2bfbits(v1.y) << 16);
  p.w = (uint)f2bfbits(v1.z) | ((uint)f2bfbits(v1.w) << 16);
  return p;
}

// ---------------------------------------------------------------------------
// P0: repack per-head weights (h,d,ko) -> fp32 [n=h*64+ko][d]  (round-5 verbatim)
// ---------------------------------------------------------------------------
__global__ __launch_bounds__(256) void repack_w(
    const float* __restrict__ wq, const float* __restrict__ wk, const float* __restrict__ wv,
    float* __restrict__ wqT, float* __restrict__ wkT, float* __restrict__ wvT){
  const float* src = (blockIdx.y == 0) ? wq : (blockIdx.y == 1) ? wk : wv;
  float* dst       = (blockIdx.y == 0) ? wqT : (blockIdx.y == 1) ? wkT : wvT;
  int i = blockIdx.x * 256 + threadIdx.x;      // over 512*512, d fastest
  int n = i >> 9, d = i & 511;
  int h = n >> 6, ko = n & 63;
  dst[i] = src[((long)h * DM_ + d) * DK_ + ko];
}

// ---------------------------------------------------------------------------
// P1: transpose pw [n][k] -> pwt [k][n]  (fp32, LDS 64x64 tile, coalesced both)
// ---------------------------------------------------------------------------
__global__ __launch_bounds__(256) void transpose_pw(
    const float* __restrict__ pw, float* __restrict__ pwt){
  const int n0 = blockIdx.x * 64;
  const int k0 = blockIdx.y * 64;
  const int tid = threadIdx.x;
  __shared__ float t[64][65];
  for (int i = tid; i < 64 * 16; i += 256){
    int nn = i >> 4, c4 = (i & 15) * 4;
    float4 v = *(const float4*)(pw + (long)(n0 + nn) * DM_ + k0 + c4);
    t[nn][c4] = v.x; t[nn][c4+1] = v.y; t[nn][c4+2] = v.z; t[nn][c4+3] = v.w;
  }
  __syncthreads();
  for (int i = tid; i < 64 * 16; i += 256){
    int kk = i >> 4, c4 = (i & 15) * 4;
    float4 v;
    v.x = t[c4+0][kk]; v.y = t[c4+1][kk]; v.z = t[c4+2][kk]; v.w = t[c4+3][kk];
    *(float4*)(pwt + (long)(k0 + kk) * DM_ + n0 + c4) = v;
  }
}

// ---------------------------------------------------------------------------
// P2: W2 = lin_w[:,512:] @ pw -> fp32 [512 i][512 k] via MFMA.
// C[m][col] = sum_n A[m][n] * Bt[col][n];  A = lw2 (row stride 1024, off 512),
// Bt = pwt [k][n] (stride 512). Cast-on-stage (round-5-proven staging body).
// ---------------------------------------------------------------------------
__global__ __launch_bounds__(256) void w2_mfma(
    const float* __restrict__ lw, const float* __restrict__ pwt,
    float* __restrict__ W2){
  const int m0 = blockIdx.x * 64;
  const int n0 = blockIdx.y * 64;
  const int tid = threadIdx.x;
  const int wid = tid >> 6, lane = tid & 63;
  const int l15 = lane & 15, l4 = lane >> 4;

  __shared__ ushort as_[64 * 64];
  __shared__ ushort bs_[64 * 64];

  f32x4 acc[4];
  #pragma unroll
  for (int ct = 0; ct < 4; ++ct){ acc[ct][0]=0.f; acc[ct][1]=0.f; acc[ct][2]=0.f; acc[ct][3]=0.f; }

  for (int k0 = 0; k0 < DM_; k0 += 64){
    __syncthreads();
    for (int i = tid; i < 512; i += 256){
      int r = i >> 3, c = i & 7;
      const float* sa = lw + (long)(m0 + r) * 1024 + 512 + k0 + c * 8;
      float4 a0 = *(const float4*)(sa);
      float4 a1 = *(const float4*)(sa + 4);
      *(uint4*)((char*)as_ + r * 128 + ((c * 16) ^ ((r & 7) << 4))) = pack8(a0, a1);
      const float* sb = pwt + (long)(n0 + r) * DM_ + k0 + c * 8;
      float4 b0 = *(const float4*)(sb);
      float4 b1 = *(const float4*)(sb + 4);
      *(uint4*)((char*)bs_ + r * 128 + ((c * 16) ^ ((r & 7) << 4))) = pack8(b0, b1);
    }
    __syncthreads();

    const char* arow = (const char*)as_ + (wid * 16 + l15) * 128;
    const int swz = (l15 & 7) << 4;
    s16x8 a0 = *(const s16x8*)(arow + ((l4 * 16) ^ swz));
    s16x8 a1 = *(const s16x8*)(arow + ((64 + l4 * 16) ^ swz));
    #pragma unroll
    for (int ct = 0; ct < 4; ++ct){
      const char* brow = (const char*)bs_ + (ct * 16 + l15) * 128;
      s16x8 b0 = *(const s16x8*)(brow + ((l4 * 16) ^ swz));
      s16x8 b1 = *(const s16x8*)(brow + ((64 + l4 * 16) ^ swz));
      acc[ct] = __builtin_amdgcn_mfma_f32_16x16x32_bf16(a0, b0, acc[ct], 0, 0, 0);
      acc[ct] = __builtin_amdgcn_mfma_f32_16x16x32_bf16(a1, b1, acc[ct], 0, 0, 0);
    }
  }

  #pragma unroll
  for (int ct = 0; ct < 4; ++ct){
    int col = n0 + ct * 16 + l15;
    #pragma unroll
    for (int r = 0; r < 4; ++r){
      int m = m0 + wid * 16 + l4 * 4 + r;
      W2[(long)m * DM_ + col] = acc[ct][r];
    }
  }
}

// ---------------------------------------------------------------------------
// P3: bias2[i] = lb[i] + sum_n lin_w[i][512+n] * pb[n]   (tiny; round-6 verbatim)
// ---------------------------------------------------------------------------
__global__ __launch_bounds__(256) void bias2_k(
    const float* __restrict__ lw, const float* __restrict__ pb,
    const float* __restrict__ lb, float* __restrict__ bias2){
  int i = blockIdx.x * 256 + threadIdx.x;
  if (i >= DM_) return;
  float acc = 0.f;
  const float* row = lw + (long)i * 1024 + 512;
  for (int n = 0; n < DM_; ++n) acc += row[n] * pb[n];
  bias2[i] = lb[i] + acc;
}

// ---------------------------------------------------------------------------
// G1: head-projection GEMMs, z = 0,1,2 -> q,k,v (round-5 body, merged launch).
// A fp32 [4096][512]; Bt fp32 [512][512] ([n][d]); cast-on-stage.
// z=0 -> qhb bf16 (scaled SCALE_T); z=1 -> khb bf16; z=2 -> vh fp32.
// ---------------------------------------------------------------------------
__global__ __launch_bounds__(256) void gemm_qkv(
    const float* __restrict__ q, const float* __restrict__ k, const float* __restrict__ v,
    const float* __restrict__ wqT, const float* __restrict__ wkT, const float* __restrict__ wvT,
    ushort* __restrict__ qhb, ushort* __restrict__ khb, float* __restrict__ vh){
  const int which = blockIdx.z;
  const float* A  = (which == 0) ? q : (which == 1) ? k : v;
  const float* Bt = (which == 0) ? wqT : (which == 1) ? wkT : wvT;

  const int m0 = blockIdx.x * 64;
  const int n0 = blockIdx.y * 64;
  const int tid = threadIdx.x;
  const int wid = tid >> 6, lane = tid & 63;
  const int l15 = lane & 15, l4 = lane >> 4;

  __shared__ ushort as_[64 * 64];
  __shared__ ushort bs_[64 * 64];

  f32x4 acc[4];
  #pragma unroll
  for (int ct = 0; ct < 4; ++ct){ acc[ct][0]=0.f; acc[ct][1]=0.f; acc[ct][2]=0.f; acc[ct][3]=0.f; }

  for (int k0 = 0; k0 < DM_; k0 += 64){
    __syncthreads();
    for (int i = tid; i < 512; i += 256){
      int r = i >> 3, c = i & 7;
      const float* sa = A + (long)(m0 + r) * DM_ + k0 + c * 8;
      float4 a0 = *(const float4*)(sa);
      float4 a1 = *(const float4*)(sa + 4);
      *(uint4*)((char*)as_ + r * 128 + ((c * 16) ^ ((r & 7) << 4))) = pack8(a0, a1);
      const float* sb = Bt + (long)(n0 + r) * DM_ + k0 + c * 8;
      float4 b0 = *(const float4*)(sb);
      float4 b1 = *(const float4*)(sb + 4);
      *(uint4*)((char*)bs_ + r * 128 + ((c * 16) ^ ((r & 7) << 4))) = pack8(b0, b1);
    }
    __syncthreads();

    const char* arow = (const char*)as_ + (wid * 16 + l15) * 128;
    const int swz = (l15 & 7) << 4;
    s16x8 a0 = *(const s16x8*)(arow + ((l4 * 16) ^ swz));
    s16x8 a1 = *(const s16x8*)(arow + ((64 + l4 * 16) ^ swz));
    #pragma unroll
    for (int ct = 0; ct < 4; ++ct){
      const char* brow = (const char*)bs_ + (ct * 16 + l15) * 128;
      s16x8 b0 = *(const s16x8*)(brow + ((l4 * 16) ^ swz));
      s16x8 b1 = *(const s16x8*)(brow + ((64 + l4 * 16) ^ swz));
      acc[ct] = __builtin_amdgcn_mfma_f32_16x16x32_bf16(a0, b0, acc[ct], 0, 0, 0);
      acc[ct] = __builtin_amdgcn_mfma_f32_16x16x32_bf16(a1, b1, acc[ct], 0, 0, 0);
    }
  }

  #pragma unroll
  for (int ct = 0; ct < 4; ++ct){
    int col = n0 + ct * 16 + l15;
    int h = col >> 6, ko = col & 63;
    #pragma unroll
    for (int r = 0; r < 4; ++r){
      int m = m0 + wid * 16 + l4 * 4 + r;
      int b = m >> 11, l = m & 2047;
      long idx = (((long)h * B_ + b) * LQ_ + l) * DK_ + ko;
      if (which == 0)      qhb[idx] = f2bfbits(acc[ct][r] * SCALE_T);
      else if (which == 1) khb[idx] = f2bfbits(acc[ct][r]);
      else                 vh[idx]  = acc[ct][r];
    }
  }
}

// ---------------------------------------------------------------------------
// K2: MFMA scores + branch-free top-1 softmax (log2-space), LDS-staged K tile
// (round-5 verbatim — verified in the 178.7 µs config)
// ---------------------------------------------------------------------------
__global__ __launch_bounds__(256) void attn_top1_mfma(
    const ushort* __restrict__ qhb, const ushort* __restrict__ khb,
    float* __restrict__ pmax, int* __restrict__ amax){
  const int hb  = blockIdx.x;
  const int q0  = blockIdx.y * 64;
  const int tid = threadIdx.x;
  const int wid  = tid >> 6;
  const int lane = tid & 63;
  const int l15  = lane & 15;
  const int l4   = lane >> 4;

  __shared__ ushort ks[64 * 64];   // 8 KB, swizzled rows of 128B

  const ushort* qrow = qhb + ((long)hb * LQ_ + q0 + wid * 16 + l15) * DK_;
  s16x8 aq0 = *(const s16x8*)(qrow +  0 + l4 * 8);
  s16x8 aq1 = *(const s16x8*)(qrow + 32 + l4 * 8);

  float m[4], sum[4]; int arg[4];
  #pragma unroll
  for (int r = 0; r < 4; ++r){ m[r] = -1e30f; sum[r] = 0.f; arg[r] = 0; }

  for (int jt = 0; jt < LQ_ / 64; ++jt){
    __syncthreads();
    const ushort* kbase = khb + ((long)hb * LQ_ + jt * 64) * DK_;
    #pragma unroll
    for (int i = tid; i < 512; i += 256){
      int r = i >> 3, c = i & 7;
      uint4 val = *(const uint4*)(kbase + r * 64 + c * 8);
      *(uint4*)((char*)ks + r * 128 + ((c * 16) ^ ((r & 7) << 4))) = val;
    }
    __syncthreads();

    f32x4 acc[4];
    #pragma unroll
    for (int ct = 0; ct < 4; ++ct){
      int row = ct * 16 + l15;
      const char* base = (const char*)ks + row * 128;
      int swz = (row & 7) << 4;
      s16x8 b0 = *(const s16x8*)(base + ((l4 * 16) ^ swz));
      s16x8 b1 = *(const s16x8*)(base + ((64 + l4 * 16) ^ swz));
      f32x4 c; c[0]=0.f; c[1]=0.f; c[2]=0.f; c[3]=0.f;
      c = __builtin_amdgcn_mfma_f32_16x16x32_bf16(aq0, b0, c, 0, 0, 0);
      c = __builtin_amdgcn_mfma_f32_16x16x32_bf16(aq1, b1, c, 0, 0, 0);
      acc[ct] = c;
    }

    #pragma unroll
    for (int ct = 0; ct < 4; ++ct){
      int col = jt * 64 + ct * 16 + l15;
      #pragma unroll
      for (int r = 0; r < 4; ++r){
        float t = acc[ct][r];
        sum[r] += exp2f(t);
        bool gt = t > m[r];
        arg[r] = gt ? col : arg[r];
        m[r]   = gt ? t : m[r];
      }
    }
  }

  #pragma unroll
  for (int off = 1; off < 16; off <<= 1){
    #pragma unroll
    for (int r = 0; r < 4; ++r){
      float m2 = __shfl_xor(m[r], off);
      float s2 = __shfl_xor(sum[r], off);
      int   a2 = __shfl_xor(arg[r], off);
      sum[r] += s2;
      bool take = (m2 > m[r]) || (m2 == m[r] && a2 < arg[r]);
      arg[r] = take ? a2 : arg[r];
      m[r]   = take ? m2 : m[r];
    }
  }

  if (l15 == 0){
    #pragma unroll
    for (int r = 0; r < 4; ++r){
      long row = (long)hb * LQ_ + q0 + wid * 16 + l4 * 4 + r;
      pmax[row] = exp2f(m[r]) / sum[r];
      amax[row] = arg[r];
    }
  }
}

// ---------------------------------------------------------------------------
// K3: gather oh rows = pmax * vh[argmax]  (fp32; round-5 verbatim)
// ---------------------------------------------------------------------------
__global__ __launch_bounds__(256) void gather_oh(
    const float* __restrict__ vh, const float* __restrict__ pmax, const int* __restrict__ amax,
    float* __restrict__ oh){
  int row  = blockIdx.x * 4 + (threadIdx.x >> 6);
  int lane = threadIdx.x & 63;
  int hb = row >> 11, q = row & 2047;
  int h = hb >> 1, b = hb & 1;
  float p = pmax[row];
  int a = amax[row];
  float val = vh[((long)hb * LQ_ + a) * DK_ + lane];
  oh[((long)(b * LQ_ + q)) * DM_ + h * DK_ + lane] = p * val;
}

// ---------------------------------------------------------------------------
// G2: fused final GEMM  out0 = [q|oh] @ [lw1 | W2]^T + bias2.  K=1024.
// k0<512: A=q (stride 512), Bt=lw rows (stride 1024).
// k0>=512: A=oh (stride 512), Bt=W2 (stride 512). Cast-on-stage.
// ---------------------------------------------------------------------------
__global__ __launch_bounds__(256) void gemm_final(
    const float* __restrict__ q, const float* __restrict__ oh,
    const float* __restrict__ lw, const float* __restrict__ W2,
    const float* __restrict__ bias2, float* __restrict__ out0){
  const int m0 = blockIdx.x * 64;
  const int n0 = blockIdx.y * 64;
  const int tid = threadIdx.x;
  const int wid = tid >> 6, lane = tid & 63;
  const int l15 = lane & 15, l4 = lane >> 4;

  __shared__ ushort as_[64 * 64];
  __shared__ ushort bs_[64 * 64];

  f32x4 acc[4];
  #pragma unroll
  for (int ct = 0; ct < 4; ++ct){ acc[ct][0]=0.f; acc[ct][1]=0.f; acc[ct][2]=0.f; acc[ct][3]=0.f; }

  for (int k0 = 0; k0 < 2 * DM_; k0 += 64){
    __syncthreads();
    for (int i = tid; i < 512; i += 256){
      int r = i >> 3, c = i & 7;
      const float* sa; const float* sb;
      if (k0 < DM_){
        sa = q  + (long)(m0 + r) * DM_ + k0 + c * 8;
        sb = lw + (long)(n0 + r) * 1024 + k0 + c * 8;
      } else {
        sa = oh + (long)(m0 + r) * DM_ + (k0 - DM_) + c * 8;
        sb = W2 + (long)(n0 + r) * DM_ + (k0 - DM_) + c * 8;
      }
      float4 a0 = *(const float4*)(sa);
      float4 a1 = *(const float4*)(sa + 4);
      *(uint4*)((char*)as_ + r * 128 + ((c * 16) ^ ((r & 7) << 4))) = pack8(a0, a1);
      float4 b0 = *(const float4*)(sb);
      float4 b1 = *(const float4*)(sb + 4);
      *(uint4*)((char*)bs_ + r * 128 + ((c * 16) ^ ((r & 7) << 4))) = pack8(b0, b1);
    }
    __syncthreads();

    const char* arow = (const char*)as_ + (wid * 16 + l15) * 128;
    const int swz = (l15 & 7) << 4;
    s16x8 a0 = *(const s16x8*)(arow + ((l4 * 16) ^ swz));
    s16x8 a1 = *(const s16x8*)(arow + ((64 + l4 * 16) ^ swz));
    #pragma unroll
    for (int ct = 0; ct < 4; ++ct){
      const char* brow = (const char*)bs_ + (ct * 16 + l15) * 128;
      s16x8 b0 = *(const s16x8*)(brow + ((l4 * 16) ^ swz));
      s16x8 b1 = *(const s16x8*)(brow + ((64 + l4 * 16) ^ swz));
      acc[ct] = __builtin_amdgcn_mfma_f32_16x16x32_bf16(a0, b0, acc[ct], 0, 0, 0);
      acc[ct] = __builtin_amdgcn_mfma_f32_16x16x32_bf16(a1, b1, acc[ct], 0, 0, 0);
    }
  }

  #pragma unroll
  for (int ct = 0; ct < 4; ++ct){
    int col = n0 + ct * 16 + l15;
    float bb = bias2[col];
    #pragma unroll
    for (int r = 0; r < 4; ++r){
      int m = m0 + wid * 16 + l4 * 4 + r;
      out0[(long)m * DM_ + col] = acc[ct][r] + bb;
    }
  }
}

// ---------------------------------------------------------------------------
// K4: fused zero + scatter of the attn output region (runs LAST; verbatim).
// ---------------------------------------------------------------------------
__global__ __launch_bounds__(256) void write_attn(
    const float* __restrict__ pmax, const int* __restrict__ amax,
    float* __restrict__ attn_out){
  int row  = blockIdx.x * 4 + (threadIdx.x >> 6);
  int lane = threadIdx.x & 63;
  float p = pmax[row];
  int a = amax[row];
  float4* rowp = (float4*)(attn_out + (long)row * LQ_);
  #pragma unroll
  for (int i = 0; i < 8; ++i){
    int f4idx = i * 64 + lane;        // 512 float4s per row
    int col0  = f4idx * 4;
    float4 z = make_float4(0.f, 0.f, 0.f, 0.f);
    if (a >= col0 && a < col0 + 4){
      int r = a - col0;
      if      (r == 0) z.x = p;
      else if (r == 1) z.y = p;
      else if (r == 2) z.z = p;
      else             z.w = p;
    }
    rowp[f4idx] = z;
  }
}

// ---------------------------------------------------------------------------
extern "C" void kernel_launch(void* const* d_in, const int* in_sizes, int n_in,
                              void* d_out, int out_size, void* d_ws, size_t ws_size,
                              hipStream_t stream){
  const float* q  = (const float*)d_in[0];
  const float* k  = (const float*)d_in[1];
  const float* v  = (const float*)d_in[2];
  const float* wq = (const float*)d_in[3];
  const float* wk = (const float*)d_in[4];
  const float* wv = (const float*)d_in[5];
  const float* pw = (const float*)d_in[6];
  const float* pb = (const float*)d_in[7];
  const float* lw = (const float*)d_in[8];
  const float* lb = (const float*)d_in[9];

  float* out0     = (float*)d_out;                    // (2,2048,512)
  float* attn_out = out0 + (long)B_ * LQ_ * DM_;      // (16,2048,2048) = 67.1M floats

  // Scratch lives INSIDE the attn output region; all dead before write_attn.
  float* vh   = attn_out;                             // 2M floats (8 MB)
  float* oh   = vh  + (long)HB_ * LQ_ * DK_;          // 2M floats (8 MB)
  float* wqT  = oh  + (long)B_ * LQ_ * DM_;           // 256K floats (1 MB)
  float* wkT  = wqT + (long)DM_ * DM_;
  float* wvT  = wkT + (long)DM_ * DM_;
  float* pwt  = wvT + (long)DM_ * DM_;                // 256K floats (1 MB)
  float* W2   = pwt + (long)DM_ * DM_;                // 256K floats (1 MB)
  float* bias2= W2  + (long)DM_ * DM_;                // 512 floats
  ushort* qhb = (ushort*)(bias2 + DM_);               // 2M bf16 (4 MB)
  ushort* khb = qhb + (long)HB_ * LQ_ * DK_;          // 2M bf16 (4 MB)
  // total ~29 MB << 268 MB region

  // d_ws: per-row stats (256 KB) — must survive write_attn.
  float* pmax = (float*)d_ws;                          // 16*2048 floats
  int*   amax = (int*)(pmax + (long)HB_ * LQ_);        // 16*2048 ints

  // prep (all tiny)
  repack_w<<<dim3(DM_*DM_/256, 3), 256, 0, stream>>>(wq, wk, wv, wqT, wkT, wvT);
  transpose_pw<<<dim3(8, 8), 256, 0, stream>>>(pw, pwt);
  w2_mfma<<<dim3(8, 8), 256, 0, stream>>>(lw, pwt, W2);
  bias2_k<<<2, 256, 0, stream>>>(lw, pb, lb, bias2);

  // head projections via one merged MFMA GEMM launch (z = q,k,v)
  gemm_qkv<<<dim3(64, 8, 3), 256, 0, stream>>>(q, k, v, wqT, wkT, wvT, qhb, khb, vh);

  // MFMA scores + branch-free top-1 softmax (LDS-staged)
  attn_top1_mfma<<<dim3(HB_, LQ_/64), 256, 0, stream>>>(qhb, khb, pmax, amax);

  // gather PV rows (fp32)
  gather_oh<<<HB_*LQ_/4, 256, 0, stream>>>(vh, pmax, amax, oh);

  // fused proj+lin: out0 = [q|oh] @ [lw1 | W2]^T + bias2
  gemm_final<<<dim3(64, 8), 256, 0, stream>>>(q, oh, lw, W2, bias2, out0);

  // LAST: rewrite the whole attn region with zeros + scattered p values
  write_attn<<<HB_*LQ_/4, 256, 0, stream>>>(pmax, amax, attn_out);
}

// Round 8
// 168.830 us; speedup vs baseline: 1.3723x; 1.0650x over previous
//
#include <hip/hip_runtime.h>
#include <hip/hip_bf16.h>

// Problem constants
#define B_   2
#define LQ_  2048
#define NH_  8
#define HB_  16      // NH_*B_
#define DM_  512
#define DK_  64

// temper = sqrt(d_model); scores computed in log2-space:
// SCALE_T = (1/sqrt(512)) * log2(e), folded into Q at projection time
#define SCALE_T (0.04419417382415922f * 1.4426950408889634f)

typedef short s16x8 __attribute__((ext_vector_type(8)));   // 8 bf16 (4 VGPRs)
typedef float f32x4 __attribute__((ext_vector_type(4)));   // MFMA 16x16 C/D

__device__ __forceinline__ ushort f2bfbits(float f){
  __hip_bfloat16 h = __float2bfloat16(f);
  union { __hip_bfloat16 h; ushort u; } cv; cv.h = h; return cv.u;
}
__device__ __forceinline__ uint4 pack8(float4 v0, float4 v1){
  uint4 p;
  p.x = (uint)f2bfbits(v0.x) | ((uint)f2bfbits(v0.y) << 16);
  p.y = (uint)f2bfbits(v0.z) | ((uint)f2bfbits(v0.w) << 16);
  p.z = (uint)f2bfbits(v1.x) | ((uint)f2bfbits(v1.y) << 16);
  p.w = (uint)f2bfbits(v1.z) | ((uint)f2bfbits(v1.w) << 16);
  return p;
}

// ---------------------------------------------------------------------------
// P0: unified prep kernel. grid (64, 6), 256 thr.
// z=0,1,2: repack w{q,k,v} (h,d,ko) fp32 -> bf16 [n=h*64+ko][d] via LDS transpose
// z=3    : transpose pw [n][k] fp32 -> pwt [k][n] fp32
// z=4    : bias2[i] = lb[i] + sum_n lw[i][512+n]*pb[n]   (x<2 only)
// z=5    : cast lw[:, :512] -> bf16 lwb1 [512][512]
// ---------------------------------------------------------------------------
__global__ __launch_bounds__(256) void prep_all(
    const float* __restrict__ wq, const float* __restrict__ wk, const float* __restrict__ wv,
    const float* __restrict__ pw, const float* __restrict__ lw,
    const float* __restrict__ pb, const float* __restrict__ lb,
    ushort* __restrict__ wqT, ushort* __restrict__ wkT, ushort* __restrict__ wvT,
    float* __restrict__ pwt, float* __restrict__ bias2, ushort* __restrict__ lwb1){
  const int z = blockIdx.z;
  const int x = blockIdx.x;
  const int tid = threadIdx.x;
  __shared__ float t[64][65];

  if (z < 3){
    const float* src = (z == 0) ? wq : (z == 1) ? wk : wv;
    ushort* dst      = (z == 0) ? wqT : (z == 1) ? wkT : wvT;
    const int h  = x >> 3;
    const int d0 = (x & 7) * 64;
    // read 64 d-rows x 64 ko (contiguous 256B rows), coalesced
    for (int i = tid; i < 64 * 16; i += 256){
      int dd = i >> 4, c4 = (i & 15) * 4;
      float4 v = *(const float4*)(src + ((long)(h * DM_ + d0 + dd)) * DK_ + c4);
      t[dd][c4] = v.x; t[dd][c4+1] = v.y; t[dd][c4+2] = v.z; t[dd][c4+3] = v.w;
    }
    __syncthreads();
    // write transposed: row n=h*64+ko, cols d0+dd (bf16 ushort4 stores)
    for (int i = tid; i < 64 * 16; i += 256){
      int ko = i >> 4, g = (i & 15) * 4;
      ushort4 u;
      u.x = f2bfbits(t[g+0][ko]); u.y = f2bfbits(t[g+1][ko]);
      u.z = f2bfbits(t[g+2][ko]); u.w = f2bfbits(t[g+3][ko]);
      *(ushort4*)(dst + ((long)(h * DK_ + ko)) * DM_ + d0 + g) = u;
    }
  } else if (z == 3){
    const int n0 = (x >> 3) * 64;
    const int k0 = (x & 7) * 64;
    for (int i = tid; i < 64 * 16; i += 256){
      int nn = i >> 4, c4 = (i & 15) * 4;
      float4 v = *(const float4*)(pw + (long)(n0 + nn) * DM_ + k0 + c4);
      t[nn][c4] = v.x; t[nn][c4+1] = v.y; t[nn][c4+2] = v.z; t[nn][c4+3] = v.w;
    }
    __syncthreads();
    for (int i = tid; i < 64 * 16; i += 256){
      int kk = i >> 4, c4 = (i & 15) * 4;
      float4 v;
      v.x = t[c4+0][kk]; v.y = t[c4+1][kk]; v.z = t[c4+2][kk]; v.w = t[c4+3][kk];
      *(float4*)(pwt + (long)(k0 + kk) * DM_ + n0 + c4) = v;
    }
  } else if (z == 4){
    if (x >= 2) return;
    int i = x * 256 + tid;
    float acc = 0.f;
    const float* row = lw + (long)i * 1024 + 512;
    for (int n = 0; n < DM_; ++n) acc += row[n] * pb[n];
    bias2[i] = lb[i] + acc;
  } else {
    // cast lw[:, :512] -> bf16 (rows 512, cols 512); 64 blocks x 256 thr x 2 reps x 8 elts
    for (int rep = 0; rep < 2; ++rep){
      int idx = rep * 16384 + x * 256 + tid;     // over 32768 groups of 8
      int row = idx >> 6, g = (idx & 63) * 8;
      const float* s = lw + (long)row * 1024 + g;
      float4 a = *(const float4*)(s);
      float4 b = *(const float4*)(s + 4);
      *(uint4*)(lwb1 + (long)row * DM_ + g) = pack8(a, b);
    }
  }
}

// ---------------------------------------------------------------------------
// P2: W2 = lin_w[:,512:] @ pw -> bf16 [512 i][512 k] via MFMA (tiny, 64 blocks)
// A = lw2 fp32 (row stride 1024, off 512), Bt = pwt fp32 [k][n]; cast-on-stage.
// ---------------------------------------------------------------------------
__global__ __launch_bounds__(256) void w2_mfma(
    const float* __restrict__ lw, const float* __restrict__ pwt,
    ushort* __restrict__ w2b){
  const int m0 = blockIdx.x * 64;
  const int n0 = blockIdx.y * 64;
  const int tid = threadIdx.x;
  const int wid = tid >> 6, lane = tid & 63;
  const int l15 = lane & 15, l4 = lane >> 4;

  __shared__ ushort as_[64 * 64];
  __shared__ ushort bs_[64 * 64];

  f32x4 acc[4];
  #pragma unroll
  for (int ct = 0; ct < 4; ++ct){ acc[ct][0]=0.f; acc[ct][1]=0.f; acc[ct][2]=0.f; acc[ct][3]=0.f; }

  for (int k0 = 0; k0 < DM_; k0 += 64){
    __syncthreads();
    for (int i = tid; i < 512; i += 256){
      int r = i >> 3, c = i & 7;
      const float* sa = lw + (long)(m0 + r) * 1024 + 512 + k0 + c * 8;
      float4 a0 = *(const float4*)(sa);
      float4 a1 = *(const float4*)(sa + 4);
      *(uint4*)((char*)as_ + r * 128 + ((c * 16) ^ ((r & 7) << 4))) = pack8(a0, a1);
      const float* sb = pwt + (long)(n0 + r) * DM_ + k0 + c * 8;
      float4 b0 = *(const float4*)(sb);
      float4 b1 = *(const float4*)(sb + 4);
      *(uint4*)((char*)bs_ + r * 128 + ((c * 16) ^ ((r & 7) << 4))) = pack8(b0, b1);
    }
    __syncthreads();

    const char* arow = (const char*)as_ + (wid * 16 + l15) * 128;
    const int swz = (l15 & 7) << 4;
    s16x8 a0 = *(const s16x8*)(arow + ((l4 * 16) ^ swz));
    s16x8 a1 = *(const s16x8*)(arow + ((64 + l4 * 16) ^ swz));
    #pragma unroll
    for (int ct = 0; ct < 4; ++ct){
      const char* brow = (const char*)bs_ + (ct * 16 + l15) * 128;
      s16x8 b0 = *(const s16x8*)(brow + ((l4 * 16) ^ swz));
      s16x8 b1 = *(const s16x8*)(brow + ((64 + l4 * 16) ^ swz));
      acc[ct] = __builtin_amdgcn_mfma_f32_16x16x32_bf16(a0, b0, acc[ct], 0, 0, 0);
      acc[ct] = __builtin_amdgcn_mfma_f32_16x16x32_bf16(a1, b1, acc[ct], 0, 0, 0);
    }
  }

  #pragma unroll
  for (int ct = 0; ct < 4; ++ct){
    int col = n0 + ct * 16 + l15;
    #pragma unroll
    for (int r = 0; r < 4; ++r){
      int m = m0 + wid * 16 + l4 * 4 + r;
      w2b[(long)m * DM_ + col] = f2bfbits(acc[ct][r]);
    }
  }
}

// ---------------------------------------------------------------------------
// G1: head-projection GEMMs, grid (512, 1, 3): z -> q,k,v.
// XCD-chunked swizzle, n0-fastest: the 8 blocks sharing an A-panel run on the
// same XCD (A fetched once per XCD; weights L2-resident).
// A fp32 [4096][512] cast-on-stage; Bt bf16 [512][512] pure-copy stage.
// z=0 -> qhb bf16 (scaled SCALE_T); z=1 -> khb bf16; z=2 -> vh fp32.
// ---------------------------------------------------------------------------
__global__ __launch_bounds__(256) void gemm_qkv(
    const float* __restrict__ q, const float* __restrict__ k, const float* __restrict__ v,
    const ushort* __restrict__ wqT, const ushort* __restrict__ wkT, const ushort* __restrict__ wvT,
    ushort* __restrict__ qhb, ushort* __restrict__ khb, float* __restrict__ vh){
  const int which = blockIdx.z;
  const float* A   = (which == 0) ? q : (which == 1) ? k : v;
  const ushort* Bt = (which == 0) ? wqT : (which == 1) ? wkT : wvT;

  // chunked XCD swizzle: bid -> logical tile (m0-major, n0-minor)
  const int bid = blockIdx.x;                 // [0,512)
  const int lt  = (bid & 7) * 64 + (bid >> 3);
  const int m0  = (lt >> 3) * 64;
  const int n0  = (lt & 7) * 64;

  const int tid = threadIdx.x;
  const int wid = tid >> 6, lane = tid & 63;
  const int l15 = lane & 15, l4 = lane >> 4;

  __shared__ ushort as_[64 * 64];
  __shared__ ushort bs_[64 * 64];

  f32x4 acc[4];
  #pragma unroll
  for (int ct = 0; ct < 4; ++ct){ acc[ct][0]=0.f; acc[ct][1]=0.f; acc[ct][2]=0.f; acc[ct][3]=0.f; }

  for (int k0 = 0; k0 < DM_; k0 += 64){
    __syncthreads();
    for (int i = tid; i < 512; i += 256){
      int r = i >> 3, c = i & 7;
      const float* sa = A + (long)(m0 + r) * DM_ + k0 + c * 8;
      float4 a0 = *(const float4*)(sa);
      float4 a1 = *(const float4*)(sa + 4);
      *(uint4*)((char*)as_ + r * 128 + ((c * 16) ^ ((r & 7) << 4))) = pack8(a0, a1);
      uint4 bv = *(const uint4*)(Bt + (long)(n0 + r) * DM_ + k0 + c * 8);
      *(uint4*)((char*)bs_ + r * 128 + ((c * 16) ^ ((r & 7) << 4))) = bv;
    }
    __syncthreads();

    const char* arow = (const char*)as_ + (wid * 16 + l15) * 128;
    const int swz = (l15 & 7) << 4;
    s16x8 a0 = *(const s16x8*)(arow + ((l4 * 16) ^ swz));
    s16x8 a1 = *(const s16x8*)(arow + ((64 + l4 * 16) ^ swz));
    #pragma unroll
    for (int ct = 0; ct < 4; ++ct){
      const char* brow = (const char*)bs_ + (ct * 16 + l15) * 128;
      s16x8 b0 = *(const s16x8*)(brow + ((l4 * 16) ^ swz));
      s16x8 b1 = *(const s16x8*)(brow + ((64 + l4 * 16) ^ swz));
      acc[ct] = __builtin_amdgcn_mfma_f32_16x16x32_bf16(a0, b0, acc[ct], 0, 0, 0);
      acc[ct] = __builtin_amdgcn_mfma_f32_16x16x32_bf16(a1, b1, acc[ct], 0, 0, 0);
    }
  }

  #pragma unroll
  for (int ct = 0; ct < 4; ++ct){
    int col = n0 + ct * 16 + l15;
    int h = col >> 6, ko = col & 63;
    #pragma unroll
    for (int r = 0; r < 4; ++r){
      int m = m0 + wid * 16 + l4 * 4 + r;
      int b = m >> 11, l = m & 2047;
      long idx = (((long)h * B_ + b) * LQ_ + l) * DK_ + ko;
      if (which == 0)      qhb[idx] = f2bfbits(acc[ct][r] * SCALE_T);
      else if (which == 1) khb[idx] = f2bfbits(acc[ct][r]);
      else                 vh[idx]  = acc[ct][r];
    }
  }
}

// ---------------------------------------------------------------------------
// K2: MFMA scores + branch-free top-1 softmax (log2-space), LDS-staged K tile
// (verified body; same-XCD per head already holds: bid%8 == hb%8)
// ---------------------------------------------------------------------------
__global__ __launch_bounds__(256) void attn_top1_mfma(
    const ushort* __restrict__ qhb, const ushort* __restrict__ khb,
    float* __restrict__ pmax, int* __restrict__ amax){
  const int hb  = blockIdx.x;
  const int q0  = blockIdx.y * 64;
  const int tid = threadIdx.x;
  const int wid  = tid >> 6;
  const int lane = tid & 63;
  const int l15  = lane & 15;
  const int l4   = lane >> 4;

  __shared__ ushort ks[64 * 64];   // 8 KB, swizzled rows of 128B

  const ushort* qrow = qhb + ((long)hb * LQ_ + q0 + wid * 16 + l15) * DK_;
  s16x8 aq0 = *(const s16x8*)(qrow +  0 + l4 * 8);
  s16x8 aq1 = *(const s16x8*)(qrow + 32 + l4 * 8);

  float m[4], sum[4]; int arg[4];
  #pragma unroll
  for (int r = 0; r < 4; ++r){ m[r] = -1e30f; sum[r] = 0.f; arg[r] = 0; }

  for (int jt = 0; jt < LQ_ / 64; ++jt){
    __syncthreads();
    const ushort* kbase = khb + ((long)hb * LQ_ + jt * 64) * DK_;
    #pragma unroll
    for (int i = tid; i < 512; i += 256){
      int r = i >> 3, c = i & 7;
      uint4 val = *(const uint4*)(kbase + r * 64 + c * 8);
      *(uint4*)((char*)ks + r * 128 + ((c * 16) ^ ((r & 7) << 4))) = val;
    }
    __syncthreads();

    f32x4 acc[4];
    #pragma unroll
    for (int ct = 0; ct < 4; ++ct){
      int row = ct * 16 + l15;
      const char* base = (const char*)ks + row * 128;
      int swz = (row & 7) << 4;
      s16x8 b0 = *(const s16x8*)(base + ((l4 * 16) ^ swz));
      s16x8 b1 = *(const s16x8*)(base + ((64 + l4 * 16) ^ swz));
      f32x4 c; c[0]=0.f; c[1]=0.f; c[2]=0.f; c[3]=0.f;
      c = __builtin_amdgcn_mfma_f32_16x16x32_bf16(aq0, b0, c, 0, 0, 0);
      c = __builtin_amdgcn_mfma_f32_16x16x32_bf16(aq1, b1, c, 0, 0, 0);
      acc[ct] = c;
    }

    #pragma unroll
    for (int ct = 0; ct < 4; ++ct){
      int col = jt * 64 + ct * 16 + l15;
      #pragma unroll
      for (int r = 0; r < 4; ++r){
        float t = acc[ct][r];
        sum[r] += exp2f(t);
        bool gt = t > m[r];
        arg[r] = gt ? col : arg[r];
        m[r]   = gt ? t : m[r];
      }
    }
  }

  #pragma unroll
  for (int off = 1; off < 16; off <<= 1){
    #pragma unroll
    for (int r = 0; r < 4; ++r){
      float m2 = __shfl_xor(m[r], off);
      float s2 = __shfl_xor(sum[r], off);
      int   a2 = __shfl_xor(arg[r], off);
      sum[r] += s2;
      bool take = (m2 > m[r]) || (m2 == m[r] && a2 < arg[r]);
      arg[r] = take ? a2 : arg[r];
      m[r]   = take ? m2 : m[r];
    }
  }

  if (l15 == 0){
    #pragma unroll
    for (int r = 0; r < 4; ++r){
      long row = (long)hb * LQ_ + q0 + wid * 16 + l4 * 4 + r;
      pmax[row] = exp2f(m[r]) / sum[r];
      amax[row] = arg[r];
    }
  }
}

// ---------------------------------------------------------------------------
// K3: gather oh rows = pmax * vh[argmax]  (fp32; verified)
// ---------------------------------------------------------------------------
__global__ __launch_bounds__(256) void gather_oh(
    const float* __restrict__ vh, const float* __restrict__ pmax, const int* __restrict__ amax,
    float* __restrict__ oh){
  int row  = blockIdx.x * 4 + (threadIdx.x >> 6);
  int lane = threadIdx.x & 63;
  int hb = row >> 11, q = row & 2047;
  int h = hb >> 1, b = hb & 1;
  float p = pmax[row];
  int a = amax[row];
  float val = vh[((long)hb * LQ_ + a) * DK_ + lane];
  oh[((long)(b * LQ_ + q)) * DM_ + h * DK_ + lane] = p * val;
}

// ---------------------------------------------------------------------------
// G2: fused final GEMM  out0 = [q|oh] @ [lwb1 | w2b]^T + bias2.  K=1024.
// Same chunked XCD swizzle. A fp32 cast-on-stage; B bf16 pure-copy stage.
// ---------------------------------------------------------------------------
__global__ __launch_bounds__(256) void gemm_final(
    const float* __restrict__ q, const float* __restrict__ oh,
    const ushort* __restrict__ lwb1, const ushort* __restrict__ w2b,
    const float* __restrict__ bias2, float* __restrict__ out0){
  const int bid = blockIdx.x;                 // [0,512)
  const int lt  = (bid & 7) * 64 + (bid >> 3);
  const int m0  = (lt >> 3) * 64;
  const int n0  = (lt & 7) * 64;

  const int tid = threadIdx.x;
  const int wid = tid >> 6, lane = tid & 63;
  const int l15 = lane & 15, l4 = lane >> 4;

  __shared__ ushort as_[64 * 64];
  __shared__ ushort bs_[64 * 64];

  f32x4 acc[4];
  #pragma unroll
  for (int ct = 0; ct < 4; ++ct){ acc[ct][0]=0.f; acc[ct][1]=0.f; acc[ct][2]=0.f; acc[ct][3]=0.f; }

  for (int k0 = 0; k0 < 2 * DM_; k0 += 64){
    const float*  Asrc = (k0 < DM_) ? q : oh;
    const ushort* Bsrc = (k0 < DM_) ? lwb1 : w2b;
    const int kk = k0 & (DM_ - 1);
    __syncthreads();
    for (int i = tid; i < 512; i += 256){
      int r = i >> 3, c = i & 7;
      const float* sa = Asrc + (long)(m0 + r) * DM_ + kk + c * 8;
      float4 a0 = *(const float4*)(sa);
      float4 a1 = *(const float4*)(sa + 4);
      *(uint4*)((char*)as_ + r * 128 + ((c * 16) ^ ((r & 7) << 4))) = pack8(a0, a1);
      uint4 bv = *(const uint4*)(Bsrc + (long)(n0 + r) * DM_ + kk + c * 8);
      *(uint4*)((char*)bs_ + r * 128 + ((c * 16) ^ ((r & 7) << 4))) = bv;
    }
    __syncthreads();

    const char* arow = (const char*)as_ + (wid * 16 + l15) * 128;
    const int swz = (l15 & 7) << 4;
    s16x8 a0 = *(const s16x8*)(arow + ((l4 * 16) ^ swz));
    s16x8 a1 = *(const s16x8*)(arow + ((64 + l4 * 16) ^ swz));
    #pragma unroll
    for (int ct = 0; ct < 4; ++ct){
      const char* brow = (const char*)bs_ + (ct * 16 + l15) * 128;
      s16x8 b0 = *(const s16x8*)(brow + ((l4 * 16) ^ swz));
      s16x8 b1 = *(const s16x8*)(brow + ((64 + l4 * 16) ^ swz));
      acc[ct] = __builtin_amdgcn_mfma_f32_16x16x32_bf16(a0, b0, acc[ct], 0, 0, 0);
      acc[ct] = __builtin_amdgcn_mfma_f32_16x16x32_bf16(a1, b1, acc[ct], 0, 0, 0);
    }
  }

  #pragma unroll
  for (int ct = 0; ct < 4; ++ct){
    int col = n0 + ct * 16 + l15;
    float bb = bias2[col];
    #pragma unroll
    for (int r = 0; r < 4; ++r){
      int m = m0 + wid * 16 + l4 * 4 + r;
      out0[(long)m * DM_ + col] = acc[ct][r] + bb;
    }
  }
}

// ---------------------------------------------------------------------------
// K4: fused zero + scatter of the attn output region (runs LAST; verified).
// ---------------------------------------------------------------------------
__global__ __launch_bounds__(256) void write_attn(
    const float* __restrict__ pmax, const int* __restrict__ amax,
    float* __restrict__ attn_out){
  int row  = blockIdx.x * 4 + (threadIdx.x >> 6);
  int lane = threadIdx.x & 63;
  float p = pmax[row];
  int a = amax[row];
  float4* rowp = (float4*)(attn_out + (long)row * LQ_);
  #pragma unroll
  for (int i = 0; i < 8; ++i){
    int f4idx = i * 64 + lane;        // 512 float4s per row
    int col0  = f4idx * 4;
    float4 z = make_float4(0.f, 0.f, 0.f, 0.f);
    if (a >= col0 && a < col0 + 4){
      int r = a - col0;
      if      (r == 0) z.x = p;
      else if (r == 1) z.y = p;
      else if (r == 2) z.z = p;
      else             z.w = p;
    }
    rowp[f4idx] = z;
  }
}

// ---------------------------------------------------------------------------
extern "C" void kernel_launch(void* const* d_in, const int* in_sizes, int n_in,
                              void* d_out, int out_size, void* d_ws, size_t ws_size,
                              hipStream_t stream){
  const float* q  = (const float*)d_in[0];
  const float* k  = (const float*)d_in[1];
  const float* v  = (const float*)d_in[2];
  const float* wq = (const float*)d_in[3];
  const float* wk = (const float*)d_in[4];
  const float* wv = (const float*)d_in[5];
  const float* pw = (const float*)d_in[6];
  const float* pb = (const float*)d_in[7];
  const float* lw = (const float*)d_in[8];
  const float* lb = (const float*)d_in[9];

  float* out0     = (float*)d_out;                    // (2,2048,512)
  float* attn_out = out0 + (long)B_ * LQ_ * DM_;      // (16,2048,2048) = 67.1M floats

  // Scratch lives INSIDE the attn output region; all dead before write_attn.
  float* vh    = attn_out;                            // 2M floats (8 MB)
  float* oh    = vh  + (long)HB_ * LQ_ * DK_;         // 2M floats (8 MB)
  float* pwt   = oh  + (long)B_ * LQ_ * DM_;          // 256K floats (1 MB)
  float* bias2 = pwt + (long)DM_ * DM_;               // 512 floats
  ushort* wqT  = (ushort*)(bias2 + DM_);              // [512][512] bf16 (512 KB)
  ushort* wkT  = wqT + (long)DM_ * DM_;
  ushort* wvT  = wkT + (long)DM_ * DM_;
  ushort* lwb1 = wvT + (long)DM_ * DM_;               // [512][512] bf16
  ushort* w2b  = lwb1 + (long)DM_ * DM_;              // [512][512] bf16
  ushort* qhb  = w2b + (long)DM_ * DM_;               // head layout bf16 (4 MB)
  ushort* khb  = qhb + (long)HB_ * LQ_ * DK_;
  // total ~28 MB << 268 MB region

  // d_ws: per-row stats (256 KB) — must survive write_attn.
  float* pmax = (float*)d_ws;                          // 16*2048 floats
  int*   amax = (int*)(pmax + (long)HB_ * LQ_);        // 16*2048 ints

  // one prep launch: repack w_{q,k,v} (bf16), pw transpose, bias2, lw1 cast
  prep_all<<<dim3(64, 1, 6), 256, 0, stream>>>(
      wq, wk, wv, pw, lw, pb, lb, wqT, wkT, wvT, pwt, bias2, lwb1);

  // W2 = lw2 @ pw -> bf16
  w2_mfma<<<dim3(8, 8), 256, 0, stream>>>(lw, pwt, w2b);

  // head projections (XCD-swizzled)
  gemm_qkv<<<dim3(512, 1, 3), 256, 0, stream>>>(q, k, v, wqT, wkT, wvT, qhb, khb, vh);

  // MFMA scores + branch-free top-1 softmax
  attn_top1_mfma<<<dim3(HB_, LQ_/64), 256, 0, stream>>>(qhb, khb, pmax, amax);

  // gather PV rows (fp32)
  gather_oh<<<HB_*LQ_/4, 256, 0, stream>>>(vh, pmax, amax, oh);

  // fused proj+lin: out0 = [q|oh] @ [lwb1 | w2b]^T + bias2 (XCD-swizzled)
  gemm_final<<<512, 256, 0, stream>>>(q, oh, lwb1, w2b, bias2, out0);

  // LAST: rewrite the whole attn region with zeros + scattered p values
  write_attn<<<HB_*LQ_/4, 256, 0, stream>>>(pmax, amax, attn_out);
}

// Round 9
// 145.683 us; speedup vs baseline: 1.5903x; 1.1589x over previous
//
#include <hip/hip_runtime.h>
#include <hip/hip_bf16.h>

// Problem constants
#define B_   2
#define LQ_  2048
#define NH_  8
#define HB_  16      // NH_*B_
#define DM_  512
#define DK_  64

// temper = sqrt(d_model); scores computed in log2-space:
// SCALE_T = (1/sqrt(512)) * log2(e), folded into Q at projection time
#define SCALE_T (0.04419417382415922f * 1.4426950408889634f)

typedef short s16x8 __attribute__((ext_vector_type(8)));   // 8 bf16 (4 VGPRs)
typedef float f32x4 __attribute__((ext_vector_type(4)));   // MFMA 16x16 C/D

__device__ __forceinline__ ushort f2bfbits(float f){
  __hip_bfloat16 h = __float2bfloat16(f);
  union { __hip_bfloat16 h; ushort u; } cv; cv.h = h; return cv.u;
}
__device__ __forceinline__ uint4 pack8(float4 v0, float4 v1){
  uint4 p;
  p.x = (uint)f2bfbits(v0.x) | ((uint)f2bfbits(v0.y) << 16);
  p.y = (uint)f2bfbits(v0.z) | ((uint)f2bfbits(v0.w) << 16);
  p.z = (uint)f2bfbits(v1.x) | ((uint)f2bfbits(v1.y) << 16);
  p.w = (uint)f2bfbits(v1.z) | ((uint)f2bfbits(v1.w) << 16);
  return p;
}

// ---------------------------------------------------------------------------
// P0: unified prep kernel. grid (64, 1, 6), 256 thr.  (round-8 verified)
// z=0,1,2: repack w{q,k,v} (h,d,ko) fp32 -> bf16 [n=h*64+ko][d] via LDS transpose
// z=3    : transpose pw [n][k] fp32 -> pwt [k][n] fp32
// z=4    : bias2[i] = lb[i] + sum_n lw[i][512+n]*pb[n]   (x<2 only)
// z=5    : cast lw[:, :512] -> bf16 lwb1 [512][512]
// ---------------------------------------------------------------------------
__global__ __launch_bounds__(256) void prep_all(
    const float* __restrict__ wq, const float* __restrict__ wk, const float* __restrict__ wv,
    const float* __restrict__ pw, const float* __restrict__ lw,
    const float* __restrict__ pb, const float* __restrict__ lb,
    ushort* __restrict__ wqT, ushort* __restrict__ wkT, ushort* __restrict__ wvT,
    float* __restrict__ pwt, float* __restrict__ bias2, ushort* __restrict__ lwb1){
  const int z = blockIdx.z;
  const int x = blockIdx.x;
  const int tid = threadIdx.x;
  __shared__ float t[64][65];

  if (z < 3){
    const float* src = (z == 0) ? wq : (z == 1) ? wk : wv;
    ushort* dst      = (z == 0) ? wqT : (z == 1) ? wkT : wvT;
    const int h  = x >> 3;
    const int d0 = (x & 7) * 64;
    for (int i = tid; i < 64 * 16; i += 256){
      int dd = i >> 4, c4 = (i & 15) * 4;
      float4 v = *(const float4*)(src + ((long)(h * DM_ + d0 + dd)) * DK_ + c4);
      t[dd][c4] = v.x; t[dd][c4+1] = v.y; t[dd][c4+2] = v.z; t[dd][c4+3] = v.w;
    }
    __syncthreads();
    for (int i = tid; i < 64 * 16; i += 256){
      int ko = i >> 4, g = (i & 15) * 4;
      ushort4 u;
      u.x = f2bfbits(t[g+0][ko]); u.y = f2bfbits(t[g+1][ko]);
      u.z = f2bfbits(t[g+2][ko]); u.w = f2bfbits(t[g+3][ko]);
      *(ushort4*)(dst + ((long)(h * DK_ + ko)) * DM_ + d0 + g) = u;
    }
  } else if (z == 3){
    const int n0 = (x >> 3) * 64;
    const int k0 = (x & 7) * 64;
    for (int i = tid; i < 64 * 16; i += 256){
      int nn = i >> 4, c4 = (i & 15) * 4;
      float4 v = *(const float4*)(pw + (long)(n0 + nn) * DM_ + k0 + c4);
      t[nn][c4] = v.x; t[nn][c4+1] = v.y; t[nn][c4+2] = v.z; t[nn][c4+3] = v.w;
    }
    __syncthreads();
    for (int i = tid; i < 64 * 16; i += 256){
      int kk = i >> 4, c4 = (i & 15) * 4;
      float4 v;
      v.x = t[c4+0][kk]; v.y = t[c4+1][kk]; v.z = t[c4+2][kk]; v.w = t[c4+3][kk];
      *(float4*)(pwt + (long)(k0 + kk) * DM_ + n0 + c4) = v;
    }
  } else if (z == 4){
    if (x >= 2) return;
    int i = x * 256 + tid;
    float acc = 0.f;
    const float* row = lw + (long)i * 1024 + 512;
    for (int n = 0; n < DM_; ++n) acc += row[n] * pb[n];
    bias2[i] = lb[i] + acc;
  } else {
    for (int rep = 0; rep < 2; ++rep){
      int idx = rep * 16384 + x * 256 + tid;
      int row = idx >> 6, g = (idx & 63) * 8;
      const float* s = lw + (long)row * 1024 + g;
      float4 a = *(const float4*)(s);
      float4 b = *(const float4*)(s + 4);
      *(uint4*)(lwb1 + (long)row * DM_ + g) = pack8(a, b);
    }
  }
}

// ---------------------------------------------------------------------------
// P2: W2 = lin_w[:,512:] @ pw -> bf16 via MFMA (round-8 verified)
// ---------------------------------------------------------------------------
__global__ __launch_bounds__(256) void w2_mfma(
    const float* __restrict__ lw, const float* __restrict__ pwt,
    ushort* __restrict__ w2b){
  const int m0 = blockIdx.x * 64;
  const int n0 = blockIdx.y * 64;
  const int tid = threadIdx.x;
  const int wid = tid >> 6, lane = tid & 63;
  const int l15 = lane & 15, l4 = lane >> 4;

  __shared__ ushort as_[64 * 64];
  __shared__ ushort bs_[64 * 64];

  f32x4 acc[4];
  #pragma unroll
  for (int ct = 0; ct < 4; ++ct){ acc[ct][0]=0.f; acc[ct][1]=0.f; acc[ct][2]=0.f; acc[ct][3]=0.f; }

  for (int k0 = 0; k0 < DM_; k0 += 64){
    __syncthreads();
    for (int i = tid; i < 512; i += 256){
      int r = i >> 3, c = i & 7;
      const float* sa = lw + (long)(m0 + r) * 1024 + 512 + k0 + c * 8;
      float4 a0 = *(const float4*)(sa);
      float4 a1 = *(const float4*)(sa + 4);
      *(uint4*)((char*)as_ + r * 128 + ((c * 16) ^ ((r & 7) << 4))) = pack8(a0, a1);
      const float* sb = pwt + (long)(n0 + r) * DM_ + k0 + c * 8;
      float4 b0 = *(const float4*)(sb);
      float4 b1 = *(const float4*)(sb + 4);
      *(uint4*)((char*)bs_ + r * 128 + ((c * 16) ^ ((r & 7) << 4))) = pack8(b0, b1);
    }
    __syncthreads();

    const char* arow = (const char*)as_ + (wid * 16 + l15) * 128;
    const int swz = (l15 & 7) << 4;
    s16x8 a0 = *(const s16x8*)(arow + ((l4 * 16) ^ swz));
    s16x8 a1 = *(const s16x8*)(arow + ((64 + l4 * 16) ^ swz));
    #pragma unroll
    for (int ct = 0; ct < 4; ++ct){
      const char* brow = (const char*)bs_ + (ct * 16 + l15) * 128;
      s16x8 b0 = *(const s16x8*)(brow + ((l4 * 16) ^ swz));
      s16x8 b1 = *(const s16x8*)(brow + ((64 + l4 * 16) ^ swz));
      acc[ct] = __builtin_amdgcn_mfma_f32_16x16x32_bf16(a0, b0, acc[ct], 0, 0, 0);
      acc[ct] = __builtin_amdgcn_mfma_f32_16x16x32_bf16(a1, b1, acc[ct], 0, 0, 0);
    }
  }

  #pragma unroll
  for (int ct = 0; ct < 4; ++ct){
    int col = n0 + ct * 16 + l15;
    #pragma unroll
    for (int r = 0; r < 4; ++r){
      int m = m0 + wid * 16 + l4 * 4 + r;
      w2b[(long)m * DM_ + col] = f2bfbits(acc[ct][r]);
    }
  }
}

// ---------------------------------------------------------------------------
// G1: head-projection GEMMs (round-8 verified, XCD-chunked swizzle)
// ---------------------------------------------------------------------------
__global__ __launch_bounds__(256) void gemm_qkv(
    const float* __restrict__ q, const float* __restrict__ k, const float* __restrict__ v,
    const ushort* __restrict__ wqT, const ushort* __restrict__ wkT, const ushort* __restrict__ wvT,
    ushort* __restrict__ qhb, ushort* __restrict__ khb, float* __restrict__ vh){
  const int which = blockIdx.z;
  const float* A   = (which == 0) ? q : (which == 1) ? k : v;
  const ushort* Bt = (which == 0) ? wqT : (which == 1) ? wkT : wvT;

  const int bid = blockIdx.x;                 // [0,512)
  const int lt  = (bid & 7) * 64 + (bid >> 3);
  const int m0  = (lt >> 3) * 64;
  const int n0  = (lt & 7) * 64;

  const int tid = threadIdx.x;
  const int wid = tid >> 6, lane = tid & 63;
  const int l15 = lane & 15, l4 = lane >> 4;

  __shared__ ushort as_[64 * 64];
  __shared__ ushort bs_[64 * 64];

  f32x4 acc[4];
  #pragma unroll
  for (int ct = 0; ct < 4; ++ct){ acc[ct][0]=0.f; acc[ct][1]=0.f; acc[ct][2]=0.f; acc[ct][3]=0.f; }

  for (int k0 = 0; k0 < DM_; k0 += 64){
    __syncthreads();
    for (int i = tid; i < 512; i += 256){
      int r = i >> 3, c = i & 7;
      const float* sa = A + (long)(m0 + r) * DM_ + k0 + c * 8;
      float4 a0 = *(const float4*)(sa);
      float4 a1 = *(const float4*)(sa + 4);
      *(uint4*)((char*)as_ + r * 128 + ((c * 16) ^ ((r & 7) << 4))) = pack8(a0, a1);
      uint4 bv = *(const uint4*)(Bt + (long)(n0 + r) * DM_ + k0 + c * 8);
      *(uint4*)((char*)bs_ + r * 128 + ((c * 16) ^ ((r & 7) << 4))) = bv;
    }
    __syncthreads();

    const char* arow = (const char*)as_ + (wid * 16 + l15) * 128;
    const int swz = (l15 & 7) << 4;
    s16x8 a0 = *(const s16x8*)(arow + ((l4 * 16) ^ swz));
    s16x8 a1 = *(const s16x8*)(arow + ((64 + l4 * 16) ^ swz));
    #pragma unroll
    for (int ct = 0; ct < 4; ++ct){
      const char* brow = (const char*)bs_ + (ct * 16 + l15) * 128;
      s16x8 b0 = *(const s16x8*)(brow + ((l4 * 16) ^ swz));
      s16x8 b1 = *(const s16x8*)(brow + ((64 + l4 * 16) ^ swz));
      acc[ct] = __builtin_amdgcn_mfma_f32_16x16x32_bf16(a0, b0, acc[ct], 0, 0, 0);
      acc[ct] = __builtin_amdgcn_mfma_f32_16x16x32_bf16(a1, b1, acc[ct], 0, 0, 0);
    }
  }

  #pragma unroll
  for (int ct = 0; ct < 4; ++ct){
    int col = n0 + ct * 16 + l15;
    int h = col >> 6, ko = col & 63;
    #pragma unroll
    for (int r = 0; r < 4; ++r){
      int m = m0 + wid * 16 + l4 * 4 + r;
      int b = m >> 11, l = m & 2047;
      long idx = (((long)h * B_ + b) * LQ_ + l) * DK_ + ko;
      if (which == 0)      qhb[idx] = f2bfbits(acc[ct][r] * SCALE_T);
      else if (which == 1) khb[idx] = f2bfbits(acc[ct][r]);
      else                 vh[idx]  = acc[ct][r];
    }
  }
}

// ---------------------------------------------------------------------------
// K2: MFMA scores + branch-free top-1 softmax (round-8 verified)
// ---------------------------------------------------------------------------
__global__ __launch_bounds__(256) void attn_top1_mfma(
    const ushort* __restrict__ qhb, const ushort* __restrict__ khb,
    float* __restrict__ pmax, int* __restrict__ amax){
  const int hb  = blockIdx.x;
  const int q0  = blockIdx.y * 64;
  const int tid = threadIdx.x;
  const int wid  = tid >> 6;
  const int lane = tid & 63;
  const int l15  = lane & 15;
  const int l4   = lane >> 4;

  __shared__ ushort ks[64 * 64];

  const ushort* qrow = qhb + ((long)hb * LQ_ + q0 + wid * 16 + l15) * DK_;
  s16x8 aq0 = *(const s16x8*)(qrow +  0 + l4 * 8);
  s16x8 aq1 = *(const s16x8*)(qrow + 32 + l4 * 8);

  float m[4], sum[4]; int arg[4];
  #pragma unroll
  for (int r = 0; r < 4; ++r){ m[r] = -1e30f; sum[r] = 0.f; arg[r] = 0; }

  for (int jt = 0; jt < LQ_ / 64; ++jt){
    __syncthreads();
    const ushort* kbase = khb + ((long)hb * LQ_ + jt * 64) * DK_;
    #pragma unroll
    for (int i = tid; i < 512; i += 256){
      int r = i >> 3, c = i & 7;
      uint4 val = *(const uint4*)(kbase + r * 64 + c * 8);
      *(uint4*)((char*)ks + r * 128 + ((c * 16) ^ ((r & 7) << 4))) = val;
    }
    __syncthreads();

    f32x4 acc[4];
    #pragma unroll
    for (int ct = 0; ct < 4; ++ct){
      int row = ct * 16 + l15;
      const char* base = (const char*)ks + row * 128;
      int swz = (row & 7) << 4;
      s16x8 b0 = *(const s16x8*)(base + ((l4 * 16) ^ swz));
      s16x8 b1 = *(const s16x8*)(base + ((64 + l4 * 16) ^ swz));
      f32x4 c; c[0]=0.f; c[1]=0.f; c[2]=0.f; c[3]=0.f;
      c = __builtin_amdgcn_mfma_f32_16x16x32_bf16(aq0, b0, c, 0, 0, 0);
      c = __builtin_amdgcn_mfma_f32_16x16x32_bf16(aq1, b1, c, 0, 0, 0);
      acc[ct] = c;
    }

    #pragma unroll
    for (int ct = 0; ct < 4; ++ct){
      int col = jt * 64 + ct * 16 + l15;
      #pragma unroll
      for (int r = 0; r < 4; ++r){
        float t = acc[ct][r];
        sum[r] += exp2f(t);
        bool gt = t > m[r];
        arg[r] = gt ? col : arg[r];
        m[r]   = gt ? t : m[r];
      }
    }
  }

  #pragma unroll
  for (int off = 1; off < 16; off <<= 1){
    #pragma unroll
    for (int r = 0; r < 4; ++r){
      float m2 = __shfl_xor(m[r], off);
      float s2 = __shfl_xor(sum[r], off);
      int   a2 = __shfl_xor(arg[r], off);
      sum[r] += s2;
      bool take = (m2 > m[r]) || (m2 == m[r] && a2 < arg[r]);
      arg[r] = take ? a2 : arg[r];
      m[r]   = take ? m2 : m[r];
    }
  }

  if (l15 == 0){
    #pragma unroll
    for (int r = 0; r < 4; ++r){
      long row = (long)hb * LQ_ + q0 + wid * 16 + l4 * 4 + r;
      pmax[row] = exp2f(m[r]) / sum[r];
      amax[row] = arg[r];
    }
  }
}

// ---------------------------------------------------------------------------
// Device body: final GEMM out0 = [q | p*vh[amax]] @ [lwb1 | w2b]^T + bias2.
// Gather fused into A-staging of the second K-half (head = kk>>6 is tile-
// uniform since kk is a multiple of 64). XCD-chunked swizzle over 512 tiles.
// ---------------------------------------------------------------------------
__device__ __forceinline__ void gemm_final_body(
    int bid, const float* __restrict__ q, const float* __restrict__ vh,
    const ushort* __restrict__ lwb1, const ushort* __restrict__ w2b,
    const float* __restrict__ bias2, const float* __restrict__ pmax,
    const int* __restrict__ amax, float* __restrict__ out0){
  const int lt  = (bid & 7) * 64 + (bid >> 3);
  const int m0  = (lt >> 3) * 64;
  const int n0  = (lt & 7) * 64;

  const int tid = threadIdx.x;
  const int wid = tid >> 6, lane = tid & 63;
  const int l15 = lane & 15, l4 = lane >> 4;

  __shared__ ushort as_[64 * 64];
  __shared__ ushort bs_[64 * 64];

  f32x4 acc[4];
  #pragma unroll
  for (int ct = 0; ct < 4; ++ct){ acc[ct][0]=0.f; acc[ct][1]=0.f; acc[ct][2]=0.f; acc[ct][3]=0.f; }

  for (int k0 = 0; k0 < 2 * DM_; k0 += 64){
    __syncthreads();
    if (k0 < DM_){
      for (int i = tid; i < 512; i += 256){
        int r = i >> 3, c = i & 7;
        const float* sa = q + (long)(m0 + r) * DM_ + k0 + c * 8;
        float4 a0 = *(const float4*)(sa);
        float4 a1 = *(const float4*)(sa + 4);
        *(uint4*)((char*)as_ + r * 128 + ((c * 16) ^ ((r & 7) << 4))) = pack8(a0, a1);
        uint4 bv = *(const uint4*)(lwb1 + (long)(n0 + r) * DM_ + k0 + c * 8);
        *(uint4*)((char*)bs_ + r * 128 + ((c * 16) ^ ((r & 7) << 4))) = bv;
      }
    } else {
      const int kk = k0 - DM_;
      const int h  = kk >> 6;          // head is uniform across the tile
      for (int i = tid; i < 512; i += 256){
        int r = i >> 3, c = i & 7;
        int mm = m0 + r;
        int b = mm >> 11, l = mm & 2047;
        long hbrow = (long)(h * B_ + b) * LQ_;
        float p = pmax[hbrow + l];
        int  a  = amax[hbrow + l];
        const float* vrow = vh + (hbrow + a) * DK_ + c * 8;
        float4 a0 = *(const float4*)(vrow);
        float4 a1 = *(const float4*)(vrow + 4);
        a0.x *= p; a0.y *= p; a0.z *= p; a0.w *= p;
        a1.x *= p; a1.y *= p; a1.z *= p; a1.w *= p;
        *(uint4*)((char*)as_ + r * 128 + ((c * 16) ^ ((r & 7) << 4))) = pack8(a0, a1);
        uint4 bv = *(const uint4*)(w2b + (long)(n0 + r) * DM_ + kk + c * 8);
        *(uint4*)((char*)bs_ + r * 128 + ((c * 16) ^ ((r & 7) << 4))) = bv;
      }
    }
    __syncthreads();

    const char* arow = (const char*)as_ + (wid * 16 + l15) * 128;
    const int swz = (l15 & 7) << 4;
    s16x8 a0 = *(const s16x8*)(arow + ((l4 * 16) ^ swz));
    s16x8 a1 = *(const s16x8*)(arow + ((64 + l4 * 16) ^ swz));
    #pragma unroll
    for (int ct = 0; ct < 4; ++ct){
      const char* brow = (const char*)bs_ + (ct * 16 + l15) * 128;
      s16x8 b0 = *(const s16x8*)(brow + ((l4 * 16) ^ swz));
      s16x8 b1 = *(const s16x8*)(brow + ((64 + l4 * 16) ^ swz));
      acc[ct] = __builtin_amdgcn_mfma_f32_16x16x32_bf16(a0, b0, acc[ct], 0, 0, 0);
      acc[ct] = __builtin_amdgcn_mfma_f32_16x16x32_bf16(a1, b1, acc[ct], 0, 0, 0);
    }
  }

  #pragma unroll
  for (int ct = 0; ct < 4; ++ct){
    int col = n0 + ct * 16 + l15;
    float bb = bias2[col];
    #pragma unroll
    for (int r = 0; r < 4; ++r){
      int mm = m0 + wid * 16 + l4 * 4 + r;
      out0[(long)mm * DM_ + col] = acc[ct][r] + bb;
    }
  }
}

// ---------------------------------------------------------------------------
// Device body: zero + scatter one group of 4 attn rows (verified logic).
// ---------------------------------------------------------------------------
__device__ __forceinline__ void write_attn_body(
    int bid, const float* __restrict__ pmax, const int* __restrict__ amax,
    float* __restrict__ attn_out){
  int row  = bid * 4 + (threadIdx.x >> 6);
  int lane = threadIdx.x & 63;
  float p = pmax[row];
  int a = amax[row];
  float4* rowp = (float4*)(attn_out + (long)row * LQ_);
  #pragma unroll
  for (int i = 0; i < 8; ++i){
    int f4idx = i * 64 + lane;
    int col0  = f4idx * 4;
    float4 z = make_float4(0.f, 0.f, 0.f, 0.f);
    if (a >= col0 && a < col0 + 4){
      int r = a - col0;
      if      (r == 0) z.x = p;
      else if (r == 1) z.y = p;
      else if (r == 2) z.z = p;
      else             z.w = p;
    }
    rowp[f4idx] = z;
  }
}

// Standalone kernels (legacy path)
__global__ __launch_bounds__(256) void gemm_final_k(
    const float* __restrict__ q, const float* __restrict__ vh,
    const ushort* __restrict__ lwb1, const ushort* __restrict__ w2b,
    const float* __restrict__ bias2, const float* __restrict__ pmax,
    const int* __restrict__ amax, float* __restrict__ out0){
  gemm_final_body(blockIdx.x, q, vh, lwb1, w2b, bias2, pmax, amax, out0);
}
__global__ __launch_bounds__(256) void write_attn_k(
    const float* __restrict__ pmax, const int* __restrict__ amax,
    float* __restrict__ attn_out){
  write_attn_body(blockIdx.x, pmax, amax, attn_out);
}

// Fused heterogeneous dispatch (scratch fully in d_ws): blocks 0..511 = GEMM,
// 512..8703 = attn-region zero+scatter. No block reads the attn region.
__global__ __launch_bounds__(256) void final_fused_k(
    const float* __restrict__ q, const float* __restrict__ vh,
    const ushort* __restrict__ lwb1, const ushort* __restrict__ w2b,
    const float* __restrict__ bias2, const float* __restrict__ pmax,
    const int* __restrict__ amax, float* __restrict__ out0,
    float* __restrict__ attn_out){
  if (blockIdx.x < 512)
    gemm_final_body(blockIdx.x, q, vh, lwb1, w2b, bias2, pmax, amax, out0);
  else
    write_attn_body(blockIdx.x - 512, pmax, amax, attn_out);
}

// ---------------------------------------------------------------------------
extern "C" void kernel_launch(void* const* d_in, const int* in_sizes, int n_in,
                              void* d_out, int out_size, void* d_ws, size_t ws_size,
                              hipStream_t stream){
  const float* q  = (const float*)d_in[0];
  const float* k  = (const float*)d_in[1];
  const float* v  = (const float*)d_in[2];
  const float* wq = (const float*)d_in[3];
  const float* wk = (const float*)d_in[4];
  const float* wv = (const float*)d_in[5];
  const float* pw = (const float*)d_in[6];
  const float* pb = (const float*)d_in[7];
  const float* lw = (const float*)d_in[8];
  const float* lb = (const float*)d_in[9];

  float* out0     = (float*)d_out;                    // (2,2048,512)
  float* attn_out = out0 + (long)B_ * LQ_ * DM_;      // (16,2048,2048) = 67.1M floats

  // Stats always in d_ws (256 KB) — verified present since round 3.
  float* pmax = (float*)d_ws;                          // 16*2048 floats
  int*   amax = (int*)(pmax + (long)HB_ * LQ_);        // 16*2048 ints

  // Fused path needs vh + lwb1 + w2b + bias2 in d_ws (so the final dispatch
  // reads nothing from the attn region): 8MB + 0.5MB + 0.5MB + 2KB + stats.
  const size_t WS_FUSED_NEED = (size_t)HB_*LQ_*8        // stats
                             + (size_t)DM_*4 + 4096     // bias2 + pad
                             + (size_t)HB_*LQ_*DK_*4    // vh
                             + (size_t)DM_*DM_*2*2;     // lwb1 + w2b
  const bool fused = (ws_size >= WS_FUSED_NEED + (1u<<20));

  float *vh, *bias2; ushort *lwb1, *w2b;
  if (fused){
    float* p = (float*)(amax + (long)HB_ * LQ_);
    bias2 = p;                        p += DM_ + 256;   // pad to 16B-multiples
    vh    = p;                        p += (long)HB_ * LQ_ * DK_;
    lwb1  = (ushort*)p;
    w2b   = lwb1 + (long)DM_ * DM_;
  } else {
    vh    = attn_out;
    bias2 = vh + (long)HB_ * LQ_ * DK_;
    lwb1  = (ushort*)(bias2 + DM_ + 256);
    w2b   = lwb1 + (long)DM_ * DM_;
  }

  // Scratch only read BEFORE the final dispatch lives in the attn region.
  ushort* base = fused ? (ushort*)attn_out : (w2b + (long)DM_ * DM_);
  ushort* wqT  = base;
  ushort* wkT  = wqT + (long)DM_ * DM_;
  ushort* wvT  = wkT + (long)DM_ * DM_;
  float*  pwt  = (float*)(wvT + (long)DM_ * DM_);
  ushort* qhb  = (ushort*)(pwt + (long)DM_ * DM_);
  ushort* khb  = qhb + (long)HB_ * LQ_ * DK_;

  // prep: repack w_{q,k,v} (bf16), pw transpose, bias2, lw1 cast
  prep_all<<<dim3(64, 1, 6), 256, 0, stream>>>(
      wq, wk, wv, pw, lw, pb, lb, wqT, wkT, wvT, pwt, bias2, lwb1);

  // W2 = lw2 @ pw -> bf16
  w2_mfma<<<dim3(8, 8), 256, 0, stream>>>(lw, pwt, w2b);

  // head projections (XCD-swizzled)
  gemm_qkv<<<dim3(512, 1, 3), 256, 0, stream>>>(q, k, v, wqT, wkT, wvT, qhb, khb, vh);

  // MFMA scores + branch-free top-1 softmax
  attn_top1_mfma<<<dim3(HB_, LQ_/64), 256, 0, stream>>>(qhb, khb, pmax, amax);

  if (fused){
    // one dispatch: 512 GEMM tiles + 8192 attn-write tiles (overlap in-flight)
    final_fused_k<<<512 + HB_*LQ_/4, 256, 0, stream>>>(
        q, vh, lwb1, w2b, bias2, pmax, amax, out0, attn_out);
  } else {
    gemm_final_k<<<512, 256, 0, stream>>>(q, vh, lwb1, w2b, bias2, pmax, amax, out0);
    write_attn_k<<<HB_*LQ_/4, 256, 0, stream>>>(pmax, amax, attn_out);
  }
}

// Round 10
// 144.904 us; speedup vs baseline: 1.5989x; 1.0054x over previous
//
#include <hip/hip_runtime.h>
#include <hip/hip_bf16.h>

// Problem constants
#define B_   2
#define LQ_  2048
#define NH_  8
#define HB_  16      // NH_*B_
#define DM_  512
#define DK_  64

// temper = sqrt(d_model); scores computed in log2-space:
// SCALE_T = (1/sqrt(512)) * log2(e), folded into Q at projection time
#define SCALE_T (0.04419417382415922f * 1.4426950408889634f)

typedef short s16x8 __attribute__((ext_vector_type(8)));   // 8 bf16 (4 VGPRs)
typedef float f32x4 __attribute__((ext_vector_type(4)));   // MFMA 16x16 C/D

__device__ __forceinline__ ushort f2bfbits(float f){
  __hip_bfloat16 h = __float2bfloat16(f);
  union { __hip_bfloat16 h; ushort u; } cv; cv.h = h; return cv.u;
}
__device__ __forceinline__ uint4 pack8(float4 v0, float4 v1){
  uint4 p;
  p.x = (uint)f2bfbits(v0.x) | ((uint)f2bfbits(v0.y) << 16);
  p.y = (uint)f2bfbits(v0.z) | ((uint)f2bfbits(v0.w) << 16);
  p.z = (uint)f2bfbits(v1.x) | ((uint)f2bfbits(v1.y) << 16);
  p.w = (uint)f2bfbits(v1.z) | ((uint)f2bfbits(v1.w) << 16);
  return p;
}

// async global->LDS 16B copy (vmcnt-tracked; __syncthreads drains)
__device__ __forceinline__ void gload_lds16(const void* g, void* l){
  __builtin_amdgcn_global_load_lds(
      (const __attribute__((address_space(1))) void*)g,
      (__attribute__((address_space(3))) void*)l, 16, 0, 0);
}

// ---------------------------------------------------------------------------
// P0: unified prep kernel. grid (1024, 1, 9), 256 thr.
// z=0,1,2: cast q/k/v fp32 -> bf16 [4096][512]          (1024 blocks)
// z=3,4,5: repack w{q,k,v} fp32 -> bf16 [n=h*64+ko][d]  (x<64)
// z=6    : transpose pw [n][k] fp32 -> pwt [k][n] fp32  (x<64)
// z=7    : bias2[i] = lb[i] + sum_n lw[i][512+n]*pb[n]  (x<2)
// z=8    : cast lw[:, :512] -> bf16 lwb1 [512][512]     (x<64)
// ---------------------------------------------------------------------------
__global__ __launch_bounds__(256) void prep_all(
    const float* __restrict__ q, const float* __restrict__ k, const float* __restrict__ v,
    const float* __restrict__ wq, const float* __restrict__ wk, const float* __restrict__ wv,
    const float* __restrict__ pw, const float* __restrict__ lw,
    const float* __restrict__ pb, const float* __restrict__ lb,
    ushort* __restrict__ qb, ushort* __restrict__ kb, ushort* __restrict__ vb,
    ushort* __restrict__ wqT, ushort* __restrict__ wkT, ushort* __restrict__ wvT,
    float* __restrict__ pwt, float* __restrict__ bias2, ushort* __restrict__ lwb1){
  const int z = blockIdx.z;
  const int x = blockIdx.x;
  const int tid = threadIdx.x;
  __shared__ float t[64][65];

  if (z < 3){
    const float* src = (z == 0) ? q : (z == 1) ? k : v;
    ushort* dst      = (z == 0) ? qb : (z == 1) ? kb : vb;
    long i = (long)x * 256 + tid;     // 262144 threads, 8 elts each
    float4 a = *(const float4*)(src + i * 8);
    float4 b = *(const float4*)(src + i * 8 + 4);
    *(uint4*)(dst + i * 8) = pack8(a, b);
  } else if (z < 6){
    if (x >= 64) return;
    const float* src = (z == 3) ? wq : (z == 4) ? wk : wv;
    ushort* dst      = (z == 3) ? wqT : (z == 4) ? wkT : wvT;
    const int h  = x >> 3;
    const int d0 = (x & 7) * 64;
    for (int i = tid; i < 64 * 16; i += 256){
      int dd = i >> 4, c4 = (i & 15) * 4;
      float4 vv = *(const float4*)(src + ((long)(h * DM_ + d0 + dd)) * DK_ + c4);
      t[dd][c4] = vv.x; t[dd][c4+1] = vv.y; t[dd][c4+2] = vv.z; t[dd][c4+3] = vv.w;
    }
    __syncthreads();
    for (int i = tid; i < 64 * 16; i += 256){
      int ko = i >> 4, g = (i & 15) * 4;
      ushort4 u;
      u.x = f2bfbits(t[g+0][ko]); u.y = f2bfbits(t[g+1][ko]);
      u.z = f2bfbits(t[g+2][ko]); u.w = f2bfbits(t[g+3][ko]);
      *(ushort4*)(dst + ((long)(h * DK_ + ko)) * DM_ + d0 + g) = u;
    }
  } else if (z == 6){
    if (x >= 64) return;
    const int n0 = (x >> 3) * 64;
    const int k0 = (x & 7) * 64;
    for (int i = tid; i < 64 * 16; i += 256){
      int nn = i >> 4, c4 = (i & 15) * 4;
      float4 vv = *(const float4*)(pw + (long)(n0 + nn) * DM_ + k0 + c4);
      t[nn][c4] = vv.x; t[nn][c4+1] = vv.y; t[nn][c4+2] = vv.z; t[nn][c4+3] = vv.w;
    }
    __syncthreads();
    for (int i = tid; i < 64 * 16; i += 256){
      int kk = i >> 4, c4 = (i & 15) * 4;
      float4 vv;
      vv.x = t[c4+0][kk]; vv.y = t[c4+1][kk]; vv.z = t[c4+2][kk]; vv.w = t[c4+3][kk];
      *(float4*)(pwt + (long)(k0 + kk) * DM_ + n0 + c4) = vv;
    }
  } else if (z == 7){
    if (x >= 2) return;
    int i = x * 256 + tid;
    float acc = 0.f;
    const float* row = lw + (long)i * 1024 + 512;
    for (int n = 0; n < DM_; ++n) acc += row[n] * pb[n];
    bias2[i] = lb[i] + acc;
  } else {
    if (x >= 64) return;
    for (int rep = 0; rep < 2; ++rep){
      int idx = rep * 16384 + x * 256 + tid;
      int row = idx >> 6, g = (idx & 63) * 8;
      const float* s = lw + (long)row * 1024 + g;
      float4 a = *(const float4*)(s);
      float4 b = *(const float4*)(s + 4);
      *(uint4*)(lwb1 + (long)row * DM_ + g) = pack8(a, b);
    }
  }
}

// ---------------------------------------------------------------------------
// P2: W2 = lin_w[:,512:] @ pw -> bf16 via MFMA (round-9 verified)
// ---------------------------------------------------------------------------
__global__ __launch_bounds__(256) void w2_mfma(
    const float* __restrict__ lw, const float* __restrict__ pwt,
    ushort* __restrict__ w2b){
  const int m0 = blockIdx.x * 64;
  const int n0 = blockIdx.y * 64;
  const int tid = threadIdx.x;
  const int wid = tid >> 6, lane = tid & 63;
  const int l15 = lane & 15, l4 = lane >> 4;

  __shared__ ushort as_[64 * 64];
  __shared__ ushort bs_[64 * 64];

  f32x4 acc[4];
  #pragma unroll
  for (int ct = 0; ct < 4; ++ct){ acc[ct][0]=0.f; acc[ct][1]=0.f; acc[ct][2]=0.f; acc[ct][3]=0.f; }

  for (int k0 = 0; k0 < DM_; k0 += 64){
    __syncthreads();
    for (int i = tid; i < 512; i += 256){
      int r = i >> 3, c = i & 7;
      const float* sa = lw + (long)(m0 + r) * 1024 + 512 + k0 + c * 8;
      float4 a0 = *(const float4*)(sa);
      float4 a1 = *(const float4*)(sa + 4);
      *(uint4*)((char*)as_ + r * 128 + ((c * 16) ^ ((r & 7) << 4))) = pack8(a0, a1);
      const float* sb = pwt + (long)(n0 + r) * DM_ + k0 + c * 8;
      float4 b0 = *(const float4*)(sb);
      float4 b1 = *(const float4*)(sb + 4);
      *(uint4*)((char*)bs_ + r * 128 + ((c * 16) ^ ((r & 7) << 4))) = pack8(b0, b1);
    }
    __syncthreads();

    const char* arow = (const char*)as_ + (wid * 16 + l15) * 128;
    const int swz = (l15 & 7) << 4;
    s16x8 a0 = *(const s16x8*)(arow + ((l4 * 16) ^ swz));
    s16x8 a1 = *(const s16x8*)(arow + ((64 + l4 * 16) ^ swz));
    #pragma unroll
    for (int ct = 0; ct < 4; ++ct){
      const char* brow = (const char*)bs_ + (ct * 16 + l15) * 128;
      s16x8 b0 = *(const s16x8*)(brow + ((l4 * 16) ^ swz));
      s16x8 b1 = *(const s16x8*)(brow + ((64 + l4 * 16) ^ swz));
      acc[ct] = __builtin_amdgcn_mfma_f32_16x16x32_bf16(a0, b0, acc[ct], 0, 0, 0);
      acc[ct] = __builtin_amdgcn_mfma_f32_16x16x32_bf16(a1, b1, acc[ct], 0, 0, 0);
    }
  }

  #pragma unroll
  for (int ct = 0; ct < 4; ++ct){
    int col = n0 + ct * 16 + l15;
    #pragma unroll
    for (int r = 0; r < 4; ++r){
      int m = m0 + wid * 16 + l4 * 4 + r;
      w2b[(long)m * DM_ + col] = f2bfbits(acc[ct][r]);
    }
  }
}

// ---------------------------------------------------------------------------
// G1: head-projection GEMMs, grid (512,1,3), XCD-chunked swizzle.
// BOTH operands bf16; staged via global_load_lds (linear LDS dest,
// inverse-swizzled global source chunk c_g = c_lds ^ (r&7); read side
// keeps the (r&7)<<4 XOR — both-sides pattern).
// ---------------------------------------------------------------------------
__global__ __launch_bounds__(256) void gemm_qkv(
    const ushort* __restrict__ qb, const ushort* __restrict__ kb, const ushort* __restrict__ vb,
    const ushort* __restrict__ wqT, const ushort* __restrict__ wkT, const ushort* __restrict__ wvT,
    ushort* __restrict__ qhb, ushort* __restrict__ khb, float* __restrict__ vh){
  const int which = blockIdx.z;
  const ushort* A  = (which == 0) ? qb : (which == 1) ? kb : vb;
  const ushort* Bt = (which == 0) ? wqT : (which == 1) ? wkT : wvT;

  const int bid = blockIdx.x;                 // [0,512)
  const int lt  = (bid & 7) * 64 + (bid >> 3);
  const int m0  = (lt >> 3) * 64;
  const int n0  = (lt & 7) * 64;

  const int tid = threadIdx.x;
  const int wid = tid >> 6, lane = tid & 63;
  const int l15 = lane & 15, l4 = lane >> 4;

  __shared__ ushort as_[64 * 64];
  __shared__ ushort bs_[64 * 64];

  // per-thread staging geometry (2 slots of 16B each)
  const int i0 = tid, i1 = tid + 256;
  const int r0 = i0 >> 3, cg0 = (i0 & 7) ^ (r0 & 7);
  const int r1 = i1 >> 3, cg1 = (i1 & 7) ^ (r1 & 7);

  f32x4 acc[4];
  #pragma unroll
  for (int ct = 0; ct < 4; ++ct){ acc[ct][0]=0.f; acc[ct][1]=0.f; acc[ct][2]=0.f; acc[ct][3]=0.f; }

  for (int k0 = 0; k0 < DM_; k0 += 64){
    __syncthreads();    // protect previous tile's LDS reads
    gload_lds16(A  + (long)(m0 + r0) * DM_ + k0 + cg0 * 8, (char*)as_ + i0 * 16);
    gload_lds16(A  + (long)(m0 + r1) * DM_ + k0 + cg1 * 8, (char*)as_ + i1 * 16);
    gload_lds16(Bt + (long)(n0 + r0) * DM_ + k0 + cg0 * 8, (char*)bs_ + i0 * 16);
    gload_lds16(Bt + (long)(n0 + r1) * DM_ + k0 + cg1 * 8, (char*)bs_ + i1 * 16);
    __syncthreads();    // drains vmcnt -> tiles ready

    const char* arow = (const char*)as_ + (wid * 16 + l15) * 128;
    const int swz = (l15 & 7) << 4;
    s16x8 a0 = *(const s16x8*)(arow + ((l4 * 16) ^ swz));
    s16x8 a1 = *(const s16x8*)(arow + ((64 + l4 * 16) ^ swz));
    #pragma unroll
    for (int ct = 0; ct < 4; ++ct){
      const char* brow = (const char*)bs_ + (ct * 16 + l15) * 128;
      s16x8 b0 = *(const s16x8*)(brow + ((l4 * 16) ^ swz));
      s16x8 b1 = *(const s16x8*)(brow + ((64 + l4 * 16) ^ swz));
      acc[ct] = __builtin_amdgcn_mfma_f32_16x16x32_bf16(a0, b0, acc[ct], 0, 0, 0);
      acc[ct] = __builtin_amdgcn_mfma_f32_16x16x32_bf16(a1, b1, acc[ct], 0, 0, 0);
    }
  }

  #pragma unroll
  for (int ct = 0; ct < 4; ++ct){
    int col = n0 + ct * 16 + l15;
    int h = col >> 6, ko = col & 63;
    #pragma unroll
    for (int r = 0; r < 4; ++r){
      int m = m0 + wid * 16 + l4 * 4 + r;
      int b = m >> 11, l = m & 2047;
      long idx = (((long)h * B_ + b) * LQ_ + l) * DK_ + ko;
      if (which == 0)      qhb[idx] = f2bfbits(acc[ct][r] * SCALE_T);
      else if (which == 1) khb[idx] = f2bfbits(acc[ct][r]);
      else                 vh[idx]  = acc[ct][r];
    }
  }
}

// ---------------------------------------------------------------------------
// K2: MFMA scores + branch-free top-1 softmax; K tile staged via
// global_load_lds with the same both-sides swizzle pattern.
// ---------------------------------------------------------------------------
__global__ __launch_bounds__(256) void attn_top1_mfma(
    const ushort* __restrict__ qhb, const ushort* __restrict__ khb,
    float* __restrict__ pmax, int* __restrict__ amax){
  const int hb  = blockIdx.x;
  const int q0  = blockIdx.y * 64;
  const int tid = threadIdx.x;
  const int wid  = tid >> 6;
  const int lane = tid & 63;
  const int l15  = lane & 15;
  const int l4   = lane >> 4;

  __shared__ ushort ks[64 * 64];

  const ushort* qrow = qhb + ((long)hb * LQ_ + q0 + wid * 16 + l15) * DK_;
  s16x8 aq0 = *(const s16x8*)(qrow +  0 + l4 * 8);
  s16x8 aq1 = *(const s16x8*)(qrow + 32 + l4 * 8);

  const int i0 = tid, i1 = tid + 256;
  const int r0 = i0 >> 3, cg0 = (i0 & 7) ^ (r0 & 7);
  const int r1 = i1 >> 3, cg1 = (i1 & 7) ^ (r1 & 7);

  float m[4], sum[4]; int arg[4];
  #pragma unroll
  for (int r = 0; r < 4; ++r){ m[r] = -1e30f; sum[r] = 0.f; arg[r] = 0; }

  const ushort* kb0 = khb + (long)hb * LQ_ * DK_;
  for (int jt = 0; jt < LQ_ / 64; ++jt){
    __syncthreads();
    const ushort* kbase = kb0 + (long)(jt * 64) * DK_;
    gload_lds16(kbase + r0 * 64 + cg0 * 8, (char*)ks + i0 * 16);
    gload_lds16(kbase + r1 * 64 + cg1 * 8, (char*)ks + i1 * 16);
    __syncthreads();

    f32x4 acc[4];
    #pragma unroll
    for (int ct = 0; ct < 4; ++ct){
      int row = ct * 16 + l15;
      const char* base = (const char*)ks + row * 128;
      int swz = (row & 7) << 4;
      s16x8 b0 = *(const s16x8*)(base + ((l4 * 16) ^ swz));
      s16x8 b1 = *(const s16x8*)(base + ((64 + l4 * 16) ^ swz));
      f32x4 c; c[0]=0.f; c[1]=0.f; c[2]=0.f; c[3]=0.f;
      c = __builtin_amdgcn_mfma_f32_16x16x32_bf16(aq0, b0, c, 0, 0, 0);
      c = __builtin_amdgcn_mfma_f32_16x16x32_bf16(aq1, b1, c, 0, 0, 0);
      acc[ct] = c;
    }

    #pragma unroll
    for (int ct = 0; ct < 4; ++ct){
      int col = jt * 64 + ct * 16 + l15;
      #pragma unroll
      for (int r = 0; r < 4; ++r){
        float t = acc[ct][r];
        sum[r] += exp2f(t);
        bool gt = t > m[r];
        arg[r] = gt ? col : arg[r];
        m[r]   = gt ? t : m[r];
      }
    }
  }

  #pragma unroll
  for (int off = 1; off < 16; off <<= 1){
    #pragma unroll
    for (int r = 0; r < 4; ++r){
      float m2 = __shfl_xor(m[r], off);
      float s2 = __shfl_xor(sum[r], off);
      int   a2 = __shfl_xor(arg[r], off);
      sum[r] += s2;
      bool take = (m2 > m[r]) || (m2 == m[r] && a2 < arg[r]);
      arg[r] = take ? a2 : arg[r];
      m[r]   = take ? m2 : m[r];
    }
  }

  if (l15 == 0){
    #pragma unroll
    for (int r = 0; r < 4; ++r){
      long row = (long)hb * LQ_ + q0 + wid * 16 + l4 * 4 + r;
      pmax[row] = exp2f(m[r]) / sum[r];
      amax[row] = arg[r];
    }
  }
}

// ---------------------------------------------------------------------------
// Final GEMM body (round-9 verified): out0 = [q | p*vh[amax]] @ [lwb1|w2b]^T + bias2
// ---------------------------------------------------------------------------
__device__ __forceinline__ void gemm_final_body(
    int bid, const float* __restrict__ q, const float* __restrict__ vh,
    const ushort* __restrict__ lwb1, const ushort* __restrict__ w2b,
    const float* __restrict__ bias2, const float* __restrict__ pmax,
    const int* __restrict__ amax, float* __restrict__ out0){
  const int lt  = (bid & 7) * 64 + (bid >> 3);
  const int m0  = (lt >> 3) * 64;
  const int n0  = (lt & 7) * 64;

  const int tid = threadIdx.x;
  const int wid = tid >> 6, lane = tid & 63;
  const int l15 = lane & 15, l4 = lane >> 4;

  __shared__ ushort as_[64 * 64];
  __shared__ ushort bs_[64 * 64];

  f32x4 acc[4];
  #pragma unroll
  for (int ct = 0; ct < 4; ++ct){ acc[ct][0]=0.f; acc[ct][1]=0.f; acc[ct][2]=0.f; acc[ct][3]=0.f; }

  for (int k0 = 0; k0 < 2 * DM_; k0 += 64){
    __syncthreads();
    if (k0 < DM_){
      for (int i = tid; i < 512; i += 256){
        int r = i >> 3, c = i & 7;
        const float* sa = q + (long)(m0 + r) * DM_ + k0 + c * 8;
        float4 a0 = *(const float4*)(sa);
        float4 a1 = *(const float4*)(sa + 4);
        *(uint4*)((char*)as_ + r * 128 + ((c * 16) ^ ((r & 7) << 4))) = pack8(a0, a1);
        uint4 bv = *(const uint4*)(lwb1 + (long)(n0 + r) * DM_ + k0 + c * 8);
        *(uint4*)((char*)bs_ + r * 128 + ((c * 16) ^ ((r & 7) << 4))) = bv;
      }
    } else {
      const int kk = k0 - DM_;
      const int h  = kk >> 6;          // head is uniform across the tile
      for (int i = tid; i < 512; i += 256){
        int r = i >> 3, c = i & 7;
        int mm = m0 + r;
        int b = mm >> 11, l = mm & 2047;
        long hbrow = (long)(h * B_ + b) * LQ_;
        float p = pmax[hbrow + l];
        int  a  = amax[hbrow + l];
        const float* vrow = vh + (hbrow + a) * DK_ + c * 8;
        float4 a0 = *(const float4*)(vrow);
        float4 a1 = *(const float4*)(vrow + 4);
        a0.x *= p; a0.y *= p; a0.z *= p; a0.w *= p;
        a1.x *= p; a1.y *= p; a1.z *= p; a1.w *= p;
        *(uint4*)((char*)as_ + r * 128 + ((c * 16) ^ ((r & 7) << 4))) = pack8(a0, a1);
        uint4 bv = *(const uint4*)(w2b + (long)(n0 + r) * DM_ + kk + c * 8);
        *(uint4*)((char*)bs_ + r * 128 + ((c * 16) ^ ((r & 7) << 4))) = bv;
      }
    }
    __syncthreads();

    const char* arow = (const char*)as_ + (wid * 16 + l15) * 128;
    const int swz = (l15 & 7) << 4;
    s16x8 a0 = *(const s16x8*)(arow + ((l4 * 16) ^ swz));
    s16x8 a1 = *(const s16x8*)(arow + ((64 + l4 * 16) ^ swz));
    #pragma unroll
    for (int ct = 0; ct < 4; ++ct){
      const char* brow = (const char*)bs_ + (ct * 16 + l15) * 128;
      s16x8 b0 = *(const s16x8*)(brow + ((l4 * 16) ^ swz));
      s16x8 b1 = *(const s16x8*)(brow + ((64 + l4 * 16) ^ swz));
      acc[ct] = __builtin_amdgcn_mfma_f32_16x16x32_bf16(a0, b0, acc[ct], 0, 0, 0);
      acc[ct] = __builtin_amdgcn_mfma_f32_16x16x32_bf16(a1, b1, acc[ct], 0, 0, 0);
    }
  }

  #pragma unroll
  for (int ct = 0; ct < 4; ++ct){
    int col = n0 + ct * 16 + l15;
    float bb = bias2[col];
    #pragma unroll
    for (int r = 0; r < 4; ++r){
      int mm = m0 + wid * 16 + l4 * 4 + r;
      out0[(long)mm * DM_ + col] = acc[ct][r] + bb;
    }
  }
}

// ---------------------------------------------------------------------------
// Zero + scatter one group of 4 attn rows (round-9 verified).
// ---------------------------------------------------------------------------
__device__ __forceinline__ void write_attn_body(
    int bid, const float* __restrict__ pmax, const int* __restrict__ amax,
    float* __restrict__ attn_out){
  int row  = bid * 4 + (threadIdx.x >> 6);
  int lane = threadIdx.x & 63;
  float p = pmax[row];
  int a = amax[row];
  float4* rowp = (float4*)(attn_out + (long)row * LQ_);
  #pragma unroll
  for (int i = 0; i < 8; ++i){
    int f4idx = i * 64 + lane;
    int col0  = f4idx * 4;
    float4 z = make_float4(0.f, 0.f, 0.f, 0.f);
    if (a >= col0 && a < col0 + 4){
      int r = a - col0;
      if      (r == 0) z.x = p;
      else if (r == 1) z.y = p;
      else if (r == 2) z.z = p;
      else             z.w = p;
    }
    rowp[f4idx] = z;
  }
}

// Standalone kernels (legacy path)
__global__ __launch_bounds__(256) void gemm_final_k(
    const float* __restrict__ q, const float* __restrict__ vh,
    const ushort* __restrict__ lwb1, const ushort* __restrict__ w2b,
    const float* __restrict__ bias2, const float* __restrict__ pmax,
    const int* __restrict__ amax, float* __restrict__ out0){
  gemm_final_body(blockIdx.x, q, vh, lwb1, w2b, bias2, pmax, amax, out0);
}
__global__ __launch_bounds__(256) void write_attn_k(
    const float* __restrict__ pmax, const int* __restrict__ amax,
    float* __restrict__ attn_out){
  write_attn_body(blockIdx.x, pmax, amax, attn_out);
}

// Fused heterogeneous dispatch (scratch fully in d_ws): blocks 0..511 = GEMM,
// 512..8703 = attn-region zero+scatter. No block reads the attn region.
__global__ __launch_bounds__(256) void final_fused_k(
    const float* __restrict__ q, const float* __restrict__ vh,
    const ushort* __restrict__ lwb1, const ushort* __restrict__ w2b,
    const float* __restrict__ bias2, const float* __restrict__ pmax,
    const int* __restrict__ amax, float* __restrict__ out0,
    float* __restrict__ attn_out){
  if (blockIdx.x < 512)
    gemm_final_body(blockIdx.x, q, vh, lwb1, w2b, bias2, pmax, amax, out0);
  else
    write_attn_body(blockIdx.x - 512, pmax, amax, attn_out);
}

// ---------------------------------------------------------------------------
extern "C" void kernel_launch(void* const* d_in, const int* in_sizes, int n_in,
                              void* d_out, int out_size, void* d_ws, size_t ws_size,
                              hipStream_t stream){
  const float* q  = (const float*)d_in[0];
  const float* k  = (const float*)d_in[1];
  const float* v  = (const float*)d_in[2];
  const float* wq = (const float*)d_in[3];
  const float* wk = (const float*)d_in[4];
  const float* wv = (const float*)d_in[5];
  const float* pw = (const float*)d_in[6];
  const float* pb = (const float*)d_in[7];
  const float* lw = (const float*)d_in[8];
  const float* lb = (const float*)d_in[9];

  float* out0     = (float*)d_out;                    // (2,2048,512)
  float* attn_out = out0 + (long)B_ * LQ_ * DM_;      // (16,2048,2048) = 67.1M floats

  // Stats always in d_ws.
  float* pmax = (float*)d_ws;                          // 16*2048 floats
  int*   amax = (int*)(pmax + (long)HB_ * LQ_);        // 16*2048 ints

  // Fused path needs vh + lwb1 + w2b + bias2 in d_ws.
  const size_t WS_FUSED_NEED = (size_t)HB_*LQ_*8        // stats
                             + (size_t)DM_*4 + 4096     // bias2 + pad
                             + (size_t)HB_*LQ_*DK_*4    // vh
                             + (size_t)DM_*DM_*2*2;     // lwb1 + w2b
  const bool fused = (ws_size >= WS_FUSED_NEED + (1u<<20));

  float *vh, *bias2; ushort *lwb1, *w2b;
  if (fused){
    float* p = (float*)(amax + (long)HB_ * LQ_);
    bias2 = p;                        p += DM_ + 256;
    vh    = p;                        p += (long)HB_ * LQ_ * DK_;
    lwb1  = (ushort*)p;
    w2b   = lwb1 + (long)DM_ * DM_;
  } else {
    vh    = attn_out;
    bias2 = vh + (long)HB_ * LQ_ * DK_;
    lwb1  = (ushort*)(bias2 + DM_ + 256);
    w2b   = lwb1 + (long)DM_ * DM_;
  }

  // Scratch only read BEFORE the final dispatch lives in the attn region.
  ushort* base = fused ? (ushort*)attn_out : (w2b + (long)DM_ * DM_);
  ushort* wqT  = base;
  ushort* wkT  = wqT + (long)DM_ * DM_;
  ushort* wvT  = wkT + (long)DM_ * DM_;
  float*  pwt  = (float*)(wvT + (long)DM_ * DM_);
  ushort* qhb  = (ushort*)(pwt + (long)DM_ * DM_);
  ushort* khb  = qhb + (long)HB_ * LQ_ * DK_;
  ushort* qb   = khb + (long)HB_ * LQ_ * DK_;          // bf16 [4096][512]
  ushort* kb   = qb  + (long)4096 * DM_;
  ushort* vb   = kb  + (long)4096 * DM_;
  // attn-region scratch total ~26 MB << 268 MB

  // one prep launch: qkv casts, weight repacks, pw transpose, bias2, lw1 cast
  prep_all<<<dim3(1024, 1, 9), 256, 0, stream>>>(
      q, k, v, wq, wk, wv, pw, lw, pb, lb,
      qb, kb, vb, wqT, wkT, wvT, pwt, bias2, lwb1);

  // W2 = lw2 @ pw -> bf16
  w2_mfma<<<dim3(8, 8), 256, 0, stream>>>(lw, pwt, w2b);

  // head projections (XCD-swizzled, global_load_lds staging)
  gemm_qkv<<<dim3(512, 1, 3), 256, 0, stream>>>(qb, kb, vb, wqT, wkT, wvT, qhb, khb, vh);

  // MFMA scores + branch-free top-1 softmax (global_load_lds staging)
  attn_top1_mfma<<<dim3(HB_, LQ_/64), 256, 0, stream>>>(qhb, khb, pmax, amax);

  if (fused){
    final_fused_k<<<512 + HB_*LQ_/4, 256, 0, stream>>>(
        q, vh, lwb1, w2b, bias2, pmax, amax, out0, attn_out);
  } else {
    gemm_final_k<<<512, 256, 0, stream>>>(q, vh, lwb1, w2b, bias2, pmax, amax, out0);
    write_attn_k<<<HB_*LQ_/4, 256, 0, stream>>>(pmax, amax, attn_out);
  }
}

// Round 12
// 133.386 us; speedup vs baseline: 1.7369x; 1.0864x over previous
//
#include <hip/hip_runtime.h>
#include <hip/hip_bf16.h>

// Problem constants
#define B_   2
#define LQ_  2048
#define NH_  8
#define HB_  16      // NH_*B_
#define DM_  512
#define DK_  64

// temper = sqrt(d_model); scores computed in log2-space:
// SCALE_T = (1/sqrt(512)) * log2(e), folded into Q at projection time
#define SCALE_T (0.04419417382415922f * 1.4426950408889634f)

typedef short s16x8 __attribute__((ext_vector_type(8)));   // 8 bf16 (4 VGPRs)
typedef float f32x4 __attribute__((ext_vector_type(4)));   // MFMA 16x16 C/D

__device__ __forceinline__ ushort f2bfbits(float f){
  __hip_bfloat16 h = __float2bfloat16(f);
  union { __hip_bfloat16 h; ushort u; } cv; cv.h = h; return cv.u;
}
__device__ __forceinline__ uint4 pack8(float4 v0, float4 v1){
  uint4 p;
  p.x = (uint)f2bfbits(v0.x) | ((uint)f2bfbits(v0.y) << 16);
  p.y = (uint)f2bfbits(v0.z) | ((uint)f2bfbits(v0.w) << 16);
  p.z = (uint)f2bfbits(v1.x) | ((uint)f2bfbits(v1.y) << 16);
  p.w = (uint)f2bfbits(v1.z) | ((uint)f2bfbits(v1.w) << 16);
  return p;
}

// async global->LDS 16B copy (vmcnt-tracked; __syncthreads drains)
__device__ __forceinline__ void gload_lds16(const void* g, void* l){
  __builtin_amdgcn_global_load_lds(
      (const __attribute__((address_space(1))) void*)g,
      (__attribute__((address_space(3))) void*)l, 16, 0, 0);
}

// ---------------------------------------------------------------------------
// P0: unified prep kernel. grid (1024, 1, 9), 256 thr.  (round-10 verified)
// z=0,1,2: cast q/k/v fp32 -> bf16 [4096][512]          (1024 blocks)
// z=3,4,5: repack w{q,k,v} fp32 -> bf16 [n=h*64+ko][d]  (x<64)
// z=6    : transpose pw [n][k] fp32 -> pwt [k][n] fp32  (x<64)
// z=7    : bias2[i] = lb[i] + sum_n lw[i][512+n]*pb[n]  (x<2)
// z=8    : cast lw[:, :512] -> bf16 lwb1 [512][512]     (x<64)
// ---------------------------------------------------------------------------
__global__ __launch_bounds__(256) void prep_all(
    const float* __restrict__ q, const float* __restrict__ k, const float* __restrict__ v,
    const float* __restrict__ wq, const float* __restrict__ wk, const float* __restrict__ wv,
    const float* __restrict__ pw, const float* __restrict__ lw,
    const float* __restrict__ pb, const float* __restrict__ lb,
    ushort* __restrict__ qb, ushort* __restrict__ kb, ushort* __restrict__ vb,
    ushort* __restrict__ wqT, ushort* __restrict__ wkT, ushort* __restrict__ wvT,
    float* __restrict__ pwt, float* __restrict__ bias2, ushort* __restrict__ lwb1){
  const int z = blockIdx.z;
  const int x = blockIdx.x;
  const int tid = threadIdx.x;
  __shared__ float t[64][65];

  if (z < 3){
    const float* src = (z == 0) ? q : (z == 1) ? k : v;
    ushort* dst      = (z == 0) ? qb : (z == 1) ? kb : vb;
    long i = (long)x * 256 + tid;     // 262144 threads, 8 elts each
    float4 a = *(const float4*)(src + i * 8);
    float4 b = *(const float4*)(src + i * 8 + 4);
    *(uint4*)(dst + i * 8) = pack8(a, b);
  } else if (z < 6){
    if (x >= 64) return;
    const float* src = (z == 3) ? wq : (z == 4) ? wk : wv;
    ushort* dst      = (z == 3) ? wqT : (z == 4) ? wkT : wvT;
    const int h  = x >> 3;
    const int d0 = (x & 7) * 64;
    for (int i = tid; i < 64 * 16; i += 256){
      int dd = i >> 4, c4 = (i & 15) * 4;
      float4 vv = *(const float4*)(src + ((long)(h * DM_ + d0 + dd)) * DK_ + c4);
      t[dd][c4] = vv.x; t[dd][c4+1] = vv.y; t[dd][c4+2] = vv.z; t[dd][c4+3] = vv.w;
    }
    __syncthreads();
    for (int i = tid; i < 64 * 16; i += 256){
      int ko = i >> 4, g = (i & 15) * 4;
      ushort4 u;
      u.x = f2bfbits(t[g+0][ko]); u.y = f2bfbits(t[g+1][ko]);
      u.z = f2bfbits(t[g+2][ko]); u.w = f2bfbits(t[g+3][ko]);
      *(ushort4*)(dst + ((long)(h * DK_ + ko)) * DM_ + d0 + g) = u;
    }
  } else if (z == 6){
    if (x >= 64) return;
    const int n0 = (x >> 3) * 64;
    const int k0 = (x & 7) * 64;
    for (int i = tid; i < 64 * 16; i += 256){
      int nn = i >> 4, c4 = (i & 15) * 4;
      float4 vv = *(const float4*)(pw + (long)(n0 + nn) * DM_ + k0 + c4);
      t[nn][c4] = vv.x; t[nn][c4+1] = vv.y; t[nn][c4+2] = vv.z; t[nn][c4+3] = vv.w;
    }
    __syncthreads();
    for (int i = tid; i < 64 * 16; i += 256){
      int kk = i >> 4, c4 = (i & 15) * 4;
      float4 vv;
      vv.x = t[c4+0][kk]; vv.y = t[c4+1][kk]; vv.z = t[c4+2][kk]; vv.w = t[c4+3][kk];
      *(float4*)(pwt + (long)(k0 + kk) * DM_ + n0 + c4) = vv;
    }
  } else if (z == 7){
    if (x >= 2) return;
    int i = x * 256 + tid;
    float acc = 0.f;
    const float* row = lw + (long)i * 1024 + 512;
    for (int n = 0; n < DM_; ++n) acc += row[n] * pb[n];
    bias2[i] = lb[i] + acc;
  } else {
    if (x >= 64) return;
    for (int rep = 0; rep < 2; ++rep){
      int idx = rep * 16384 + x * 256 + tid;
      int row = idx >> 6, g = (idx & 63) * 8;
      const float* s = lw + (long)row * 1024 + g;
      float4 a = *(const float4*)(s);
      float4 b = *(const float4*)(s + 4);
      *(uint4*)(lwb1 + (long)row * DM_ + g) = pack8(a, b);
    }
  }
}

// ---------------------------------------------------------------------------
// PH2: combined head-projection GEMMs + W2 GEMM, 1600 blocks.
// blocks [0,1536): qkv tiles (which = bid/512, tile = bid%512, XCD swizzle,
//                  global_load_lds staging — round-10 gemm_qkv verbatim)
// blocks [1536,1600): W2 = lw2 @ pw tiles (round-10 w2_mfma verbatim)
// ---------------------------------------------------------------------------
__global__ __launch_bounds__(256) void phase2_k(
    const ushort* __restrict__ qb, const ushort* __restrict__ kb, const ushort* __restrict__ vb,
    const ushort* __restrict__ wqT, const ushort* __restrict__ wkT, const ushort* __restrict__ wvT,
    ushort* __restrict__ qhb, ushort* __restrict__ khb, float* __restrict__ vh,
    const float* __restrict__ lw, const float* __restrict__ pwt, ushort* __restrict__ w2b){
  const int tid = threadIdx.x;
  const int wid = tid >> 6, lane = tid & 63;
  const int l15 = lane & 15, l4 = lane >> 4;

  __shared__ ushort as_[64 * 64];
  __shared__ ushort bs_[64 * 64];

  f32x4 acc[4];
  #pragma unroll
  for (int ct = 0; ct < 4; ++ct){ acc[ct][0]=0.f; acc[ct][1]=0.f; acc[ct][2]=0.f; acc[ct][3]=0.f; }

  if (blockIdx.x < 1536){
    const int which = blockIdx.x / 512;
    const int bid   = blockIdx.x % 512;
    const ushort* A  = (which == 0) ? qb : (which == 1) ? kb : vb;
    const ushort* Bt = (which == 0) ? wqT : (which == 1) ? wkT : wvT;

    const int lt  = (bid & 7) * 64 + (bid >> 3);
    const int m0  = (lt >> 3) * 64;
    const int n0  = (lt & 7) * 64;

    const int i0 = tid, i1 = tid + 256;
    const int r0 = i0 >> 3, cg0 = (i0 & 7) ^ (r0 & 7);
    const int r1 = i1 >> 3, cg1 = (i1 & 7) ^ (r1 & 7);

    for (int k0 = 0; k0 < DM_; k0 += 64){
      __syncthreads();
      gload_lds16(A  + (long)(m0 + r0) * DM_ + k0 + cg0 * 8, (char*)as_ + i0 * 16);
      gload_lds16(A  + (long)(m0 + r1) * DM_ + k0 + cg1 * 8, (char*)as_ + i1 * 16);
      gload_lds16(Bt + (long)(n0 + r0) * DM_ + k0 + cg0 * 8, (char*)bs_ + i0 * 16);
      gload_lds16(Bt + (long)(n0 + r1) * DM_ + k0 + cg1 * 8, (char*)bs_ + i1 * 16);
      __syncthreads();

      const char* arow = (const char*)as_ + (wid * 16 + l15) * 128;
      const int swz = (l15 & 7) << 4;
      s16x8 a0 = *(const s16x8*)(arow + ((l4 * 16) ^ swz));
      s16x8 a1 = *(const s16x8*)(arow + ((64 + l4 * 16) ^ swz));
      #pragma unroll
      for (int ct = 0; ct < 4; ++ct){
        const char* brow = (const char*)bs_ + (ct * 16 + l15) * 128;
        s16x8 b0 = *(const s16x8*)(brow + ((l4 * 16) ^ swz));
        s16x8 b1 = *(const s16x8*)(brow + ((64 + l4 * 16) ^ swz));
        acc[ct] = __builtin_amdgcn_mfma_f32_16x16x32_bf16(a0, b0, acc[ct], 0, 0, 0);
        acc[ct] = __builtin_amdgcn_mfma_f32_16x16x32_bf16(a1, b1, acc[ct], 0, 0, 0);
      }
    }

    #pragma unroll
    for (int ct = 0; ct < 4; ++ct){
      int col = n0 + ct * 16 + l15;
      int h = col >> 6, ko = col & 63;
      #pragma unroll
      for (int r = 0; r < 4; ++r){
        int m = m0 + wid * 16 + l4 * 4 + r;
        int b = m >> 11, l = m & 2047;
        long idx = (((long)h * B_ + b) * LQ_ + l) * DK_ + ko;
        if (which == 0)      qhb[idx] = f2bfbits(acc[ct][r] * SCALE_T);
        else if (which == 1) khb[idx] = f2bfbits(acc[ct][r]);
        else                 vh[idx]  = acc[ct][r];
      }
    }
  } else {
    const int t_ = blockIdx.x - 1536;        // [0,64)
    const int m0 = (t_ >> 3) * 64;
    const int n0 = (t_ & 7) * 64;

    for (int k0 = 0; k0 < DM_; k0 += 64){
      __syncthreads();
      for (int i = tid; i < 512; i += 256){
        int r = i >> 3, c = i & 7;
        const float* sa = lw + (long)(m0 + r) * 1024 + 512 + k0 + c * 8;
        float4 a0 = *(const float4*)(sa);
        float4 a1 = *(const float4*)(sa + 4);
        *(uint4*)((char*)as_ + r * 128 + ((c * 16) ^ ((r & 7) << 4))) = pack8(a0, a1);
        const float* sb = pwt + (long)(n0 + r) * DM_ + k0 + c * 8;
        float4 b0 = *(const float4*)(sb);
        float4 b1 = *(const float4*)(sb + 4);
        *(uint4*)((char*)bs_ + r * 128 + ((c * 16) ^ ((r & 7) << 4))) = pack8(b0, b1);
      }
      __syncthreads();

      const char* arow = (const char*)as_ + (wid * 16 + l15) * 128;
      const int swz = (l15 & 7) << 4;
      s16x8 a0 = *(const s16x8*)(arow + ((l4 * 16) ^ swz));
      s16x8 a1 = *(const s16x8*)(arow + ((64 + l4 * 16) ^ swz));
      #pragma unroll
      for (int ct = 0; ct < 4; ++ct){
        const char* brow = (const char*)bs_ + (ct * 16 + l15) * 128;
        s16x8 b0 = *(const s16x8*)(brow + ((l4 * 16) ^ swz));
        s16x8 b1 = *(const s16x8*)(brow + ((64 + l4 * 16) ^ swz));
        acc[ct] = __builtin_amdgcn_mfma_f32_16x16x32_bf16(a0, b0, acc[ct], 0, 0, 0);
        acc[ct] = __builtin_amdgcn_mfma_f32_16x16x32_bf16(a1, b1, acc[ct], 0, 0, 0);
      }
    }

    #pragma unroll
    for (int ct = 0; ct < 4; ++ct){
      int col = n0 + ct * 16 + l15;
      #pragma unroll
      for (int r = 0; r < 4; ++r){
        int m = m0 + wid * 16 + l4 * 4 + r;
        w2b[(long)m * DM_ + col] = f2bfbits(acc[ct][r]);
      }
    }
  }
}

// ---------------------------------------------------------------------------
// K2: MFMA scores + branch-free top-1 softmax (round-10 verified)
// ---------------------------------------------------------------------------
__global__ __launch_bounds__(256) void attn_top1_mfma(
    const ushort* __restrict__ qhb, const ushort* __restrict__ khb,
    float* __restrict__ pmax, int* __restrict__ amax){
  const int hb  = blockIdx.x;
  const int q0  = blockIdx.y * 64;
  const int tid = threadIdx.x;
  const int wid  = tid >> 6;
  const int lane = tid & 63;
  const int l15  = lane & 15;
  const int l4   = lane >> 4;

  __shared__ ushort ks[64 * 64];

  const ushort* qrow = qhb + ((long)hb * LQ_ + q0 + wid * 16 + l15) * DK_;
  s16x8 aq0 = *(const s16x8*)(qrow +  0 + l4 * 8);
  s16x8 aq1 = *(const s16x8*)(qrow + 32 + l4 * 8);

  const int i0 = tid, i1 = tid + 256;
  const int r0 = i0 >> 3, cg0 = (i0 & 7) ^ (r0 & 7);
  const int r1 = i1 >> 3, cg1 = (i1 & 7) ^ (r1 & 7);

  float m[4], sum[4]; int arg[4];
  #pragma unroll
  for (int r = 0; r < 4; ++r){ m[r] = -1e30f; sum[r] = 0.f; arg[r] = 0; }

  const ushort* kb0 = khb + (long)hb * LQ_ * DK_;
  for (int jt = 0; jt < LQ_ / 64; ++jt){
    __syncthreads();
    const ushort* kbase = kb0 + (long)(jt * 64) * DK_;
    gload_lds16(kbase + r0 * 64 + cg0 * 8, (char*)ks + i0 * 16);
    gload_lds16(kbase + r1 * 64 + cg1 * 8, (char*)ks + i1 * 16);
    __syncthreads();

    f32x4 acc[4];
    #pragma unroll
    for (int ct = 0; ct < 4; ++ct){
      int row = ct * 16 + l15;
      const char* base = (const char*)ks + row * 128;
      int swz = (row & 7) << 4;
      s16x8 b0 = *(const s16x8*)(base + ((l4 * 16) ^ swz));
      s16x8 b1 = *(const s16x8*)(base + ((64 + l4 * 16) ^ swz));
      f32x4 c; c[0]=0.f; c[1]=0.f; c[2]=0.f; c[3]=0.f;
      c = __builtin_amdgcn_mfma_f32_16x16x32_bf16(aq0, b0, c, 0, 0, 0);
      c = __builtin_amdgcn_mfma_f32_16x16x32_bf16(aq1, b1, c, 0, 0, 0);
      acc[ct] = c;
    }

    #pragma unroll
    for (int ct = 0; ct < 4; ++ct){
      int col = jt * 64 + ct * 16 + l15;
      #pragma unroll
      for (int r = 0; r < 4; ++r){
        float t = acc[ct][r];
        sum[r] += exp2f(t);
        bool gt = t > m[r];
        arg[r] = gt ? col : arg[r];
        m[r]   = gt ? t : m[r];
      }
    }
  }

  #pragma unroll
  for (int off = 1; off < 16; off <<= 1){
    #pragma unroll
    for (int r = 0; r < 4; ++r){
      float m2 = __shfl_xor(m[r], off);
      float s2 = __shfl_xor(sum[r], off);
      int   a2 = __shfl_xor(arg[r], off);
      sum[r] += s2;
      bool take = (m2 > m[r]) || (m2 == m[r] && a2 < arg[r]);
      arg[r] = take ? a2 : arg[r];
      m[r]   = take ? m2 : m[r];
    }
  }

  if (l15 == 0){
    #pragma unroll
    for (int r = 0; r < 4; ++r){
      long row = (long)hb * LQ_ + q0 + wid * 16 + l4 * 4 + r;
      pmax[row] = exp2f(m[r]) / sum[r];
      amax[row] = arg[r];
    }
  }
}

// ---------------------------------------------------------------------------
// Final GEMM body (round-10 verified): out0 = [q | p*vh[amax]] @ [lwb1|w2b]^T + bias2
// ---------------------------------------------------------------------------
__device__ __forceinline__ void gemm_final_body(
    int bid, const float* __restrict__ q, const float* __restrict__ vh,
    const ushort* __restrict__ lwb1, const ushort* __restrict__ w2b,
    const float* __restrict__ bias2, const float* __restrict__ pmax,
    const int* __restrict__ amax, float* __restrict__ out0){
  const int lt  = (bid & 7) * 64 + (bid >> 3);
  const int m0  = (lt >> 3) * 64;
  const int n0  = (lt & 7) * 64;

  const int tid = threadIdx.x;
  const int wid = tid >> 6, lane = tid & 63;
  const int l15 = lane & 15, l4 = lane >> 4;

  __shared__ ushort as_[64 * 64];
  __shared__ ushort bs_[64 * 64];

  f32x4 acc[4];
  #pragma unroll
  for (int ct = 0; ct < 4; ++ct){ acc[ct][0]=0.f; acc[ct][1]=0.f; acc[ct][2]=0.f; acc[ct][3]=0.f; }

  for (int k0 = 0; k0 < 2 * DM_; k0 += 64){
    __syncthreads();
    if (k0 < DM_){
      for (int i = tid; i < 512; i += 256){
        int r = i >> 3, c = i & 7;
        const float* sa = q + (long)(m0 + r) * DM_ + k0 + c * 8;
        float4 a0 = *(const float4*)(sa);
        float4 a1 = *(const float4*)(sa + 4);
        *(uint4*)((char*)as_ + r * 128 + ((c * 16) ^ ((r & 7) << 4))) = pack8(a0, a1);
        uint4 bv = *(const uint4*)(lwb1 + (long)(n0 + r) * DM_ + k0 + c * 8);
        *(uint4*)((char*)bs_ + r * 128 + ((c * 16) ^ ((r & 7) << 4))) = bv;
      }
    } else {
      const int kk = k0 - DM_;
      const int h  = kk >> 6;          // head is uniform across the tile
      for (int i = tid; i < 512; i += 256){
        int r = i >> 3, c = i & 7;
        int mm = m0 + r;
        int b = mm >> 11, l = mm & 2047;
        long hbrow = (long)(h * B_ + b) * LQ_;
        float p = pmax[hbrow + l];
        int  a  = amax[hbrow + l];
        const float* vrow = vh + (hbrow + a) * DK_ + c * 8;
        float4 a0 = *(const float4*)(vrow);
        float4 a1 = *(const float4*)(vrow + 4);
        a0.x *= p; a0.y *= p; a0.z *= p; a0.w *= p;
        a1.x *= p; a1.y *= p; a1.z *= p; a1.w *= p;
        *(uint4*)((char*)as_ + r * 128 + ((c * 16) ^ ((r & 7) << 4))) = pack8(a0, a1);
        uint4 bv = *(const uint4*)(w2b + (long)(n0 + r) * DM_ + kk + c * 8);
        *(uint4*)((char*)bs_ + r * 128 + ((c * 16) ^ ((r & 7) << 4))) = bv;
      }
    }
    __syncthreads();

    const char* arow = (const char*)as_ + (wid * 16 + l15) * 128;
    const int swz = (l15 & 7) << 4;
    s16x8 a0 = *(const s16x8*)(arow + ((l4 * 16) ^ swz));
    s16x8 a1 = *(const s16x8*)(arow + ((64 + l4 * 16) ^ swz));
    #pragma unroll
    for (int ct = 0; ct < 4; ++ct){
      const char* brow = (const char*)bs_ + (ct * 16 + l15) * 128;
      s16x8 b0 = *(const s16x8*)(brow + ((l4 * 16) ^ swz));
      s16x8 b1 = *(const s16x8*)(brow + ((64 + l4 * 16) ^ swz));
      acc[ct] = __builtin_amdgcn_mfma_f32_16x16x32_bf16(a0, b0, acc[ct], 0, 0, 0);
      acc[ct] = __builtin_amdgcn_mfma_f32_16x16x32_bf16(a1, b1, acc[ct], 0, 0, 0);
    }
  }

  #pragma unroll
  for (int ct = 0; ct < 4; ++ct){
    int col = n0 + ct * 16 + l15;
    float bb = bias2[col];
    #pragma unroll
    for (int r = 0; r < 4; ++r){
      int mm = m0 + wid * 16 + l4 * 4 + r;
      out0[(long)mm * DM_ + col] = acc[ct][r] + bb;
    }
  }
}

// ---------------------------------------------------------------------------
// Zero + scatter one group of 4 attn rows (round-10 verified).
// ---------------------------------------------------------------------------
__device__ __forceinline__ void write_attn_body(
    int bid, const float* __restrict__ pmax, const int* __restrict__ amax,
    float* __restrict__ attn_out){
  int row  = bid * 4 + (threadIdx.x >> 6);
  int lane = threadIdx.x & 63;
  float p = pmax[row];
  int a = amax[row];
  float4* rowp = (float4*)(attn_out + (long)row * LQ_);
  #pragma unroll
  for (int i = 0; i < 8; ++i){
    int f4idx = i * 64 + lane;
    int col0  = f4idx * 4;
    float4 z = make_float4(0.f, 0.f, 0.f, 0.f);
    if (a >= col0 && a < col0 + 4){
      int r = a - col0;
      if      (r == 0) z.x = p;
      else if (r == 1) z.y = p;
      else if (r == 2) z.z = p;
      else             z.w = p;
    }
    rowp[f4idx] = z;
  }
}

// Standalone kernels (legacy path)
__global__ __launch_bounds__(256) void gemm_final_k(
    const float* __restrict__ q, const float* __restrict__ vh,
    const ushort* __restrict__ lwb1, const ushort* __restrict__ w2b,
    const float* __restrict__ bias2, const float* __restrict__ pmax,
    const int* __restrict__ amax, float* __restrict__ out0){
  gemm_final_body(blockIdx.x, q, vh, lwb1, w2b, bias2, pmax, amax, out0);
}
__global__ __launch_bounds__(256) void write_attn_k(
    const float* __restrict__ pmax, const int* __restrict__ amax,
    float* __restrict__ attn_out){
  write_attn_body(blockIdx.x, pmax, amax, attn_out);
}

// Fused heterogeneous dispatch (scratch fully in d_ws): blocks 0..511 = GEMM,
// 512..8703 = attn-region zero+scatter. No block reads the attn region.
__global__ __launch_bounds__(256) void final_fused_k(
    const float* __restrict__ q, const float* __restrict__ vh,
    const ushort* __restrict__ lwb1, const ushort* __restrict__ w2b,
    const float* __restrict__ bias2, const float* __restrict__ pmax,
    const int* __restrict__ amax, float* __restrict__ out0,
    float* __restrict__ attn_out){
  if (blockIdx.x < 512)
    gemm_final_body(blockIdx.x, q, vh, lwb1, w2b, bias2, pmax, amax, out0);
  else
    write_attn_body(blockIdx.x - 512, pmax, amax, attn_out);
}

// ---------------------------------------------------------------------------
extern "C" void kernel_launch(void* const* d_in, const int* in_sizes, int n_in,
                              void* d_out, int out_size, void* d_ws, size_t ws_size,
                              hipStream_t stream){
  const float* q  = (const float*)d_in[0];
  const float* k  = (const float*)d_in[1];
  const float* v  = (const float*)d_in[2];
  const float* wq = (const float*)d_in[3];
  const float* wk = (const float*)d_in[4];
  const float* wv = (const float*)d_in[5];
  const float* pw = (const float*)d_in[6];
  const float* pb = (const float*)d_in[7];
  const float* lw = (const float*)d_in[8];
  const float* lb = (const float*)d_in[9];

  float* out0     = (float*)d_out;                    // (2,2048,512)
  float* attn_out = out0 + (long)B_ * LQ_ * DM_;      // (16,2048,2048) = 67.1M floats

  // Stats always in d_ws.
  float* pmax = (float*)d_ws;                          // 16*2048 floats
  int*   amax = (int*)(pmax + (long)HB_ * LQ_);        // 16*2048 ints

  // Fused path needs vh + lwb1 + w2b + bias2 in d_ws.
  const size_t WS_FUSED_NEED = (size_t)HB_*LQ_*8        // stats
                             + (size_t)DM_*4 + 4096     // bias2 + pad
                             + (size_t)HB_*LQ_*DK_*4    // vh
                             + (size_t)DM_*DM_*2*2;     // lwb1 + w2b
  const bool fused = (ws_size >= WS_FUSED_NEED + (1u<<20));

  float *vh, *bias2; ushort *lwb1, *w2b;
  if (fused){
    float* p = (float*)(amax + (long)HB_ * LQ_);
    bias2 = p;                        p += DM_ + 256;
    vh    = p;                        p += (long)HB_ * LQ_ * DK_;
    lwb1  = (ushort*)p;
    w2b   = lwb1 + (long)DM_ * DM_;
  } else {
    vh    = attn_out;
    bias2 = vh + (long)HB_ * LQ_ * DK_;
    lwb1  = (ushort*)(bias2 + DM_ + 256);
    w2b   = lwb1 + (long)DM_ * DM_;
  }

  // Scratch only read BEFORE the final dispatch lives in the attn region.
  ushort* base = fused ? (ushort*)attn_out : (w2b + (long)DM_ * DM_);
  ushort* wqT  = base;
  ushort* wkT  = wqT + (long)DM_ * DM_;
  ushort* wvT  = wkT + (long)DM_ * DM_;
  float*  pwt  = (float*)(wvT + (long)DM_ * DM_);
  ushort* qhb  = (ushort*)(pwt + (long)DM_ * DM_);
  ushort* khb  = qhb + (long)HB_ * LQ_ * DK_;
  ushort* qb   = khb + (long)HB_ * LQ_ * DK_;          // bf16 [4096][512]
  ushort* kb   = qb  + (long)4096 * DM_;
  ushort* vb   = kb  + (long)4096 * DM_;
  // attn-region scratch total ~26 MB << 268 MB

  // 1) prep: qkv casts, weight repacks, pw transpose, bias2, lw1 cast
  prep_all<<<dim3(1024, 1, 9), 256, 0, stream>>>(
      q, k, v, wq, wk, wv, pw, lw, pb, lb,
      qb, kb, vb, wqT, wkT, wvT, pwt, bias2, lwb1);

  // 2) head projections + W2 in one launch (no mutual dependency)
  phase2_k<<<1600, 256, 0, stream>>>(
      qb, kb, vb, wqT, wkT, wvT, qhb, khb, vh, lw, pwt, w2b);

  // 3) MFMA scores + branch-free top-1 softmax
  attn_top1_mfma<<<dim3(HB_, LQ_/64), 256, 0, stream>>>(qhb, khb, pmax, amax);

  // 4) final GEMM + attn-region write
  if (fused){
    final_fused_k<<<512 + HB_*LQ_/4, 256, 0, stream>>>(
        q, vh, lwb1, w2b, bias2, pmax, amax, out0, attn_out);
  } else {
    gemm_final_k<<<512, 256, 0, stream>>>(q, vh, lwb1, w2b, bias2, pmax, amax, out0);
    write_attn_k<<<HB_*LQ_/4, 256, 0, stream>>>(pmax, amax, attn_out);
  }
}